// Round 1
// baseline (1018.358 us; speedup 1.0000x reference)
//
#include <hip/hip_runtime.h>
#include <math.h>

// ---------------------------------------------------------------------------
// GAT (3-layer PyG GATConv, eval) on MI355X.
// Pipeline per call (deterministic, all on `stream`):
//   CSR build: hist(deg) -> scan -> scatter (sorted by dst, self-loops appended)
//   per layer: k_gemm (xp = h @ W), k_al (attention logits), k_agg (segment
//              softmax + weighted aggregation + bias + ELU)
// ---------------------------------------------------------------------------

#define N_NODES 100000

// ------------------------------ CSR build ----------------------------------

__global__ void k_hist(const int* __restrict__ ei, int E, int ETOT, int* __restrict__ deg) {
    int i = blockIdx.x * 256 + threadIdx.x;
    if (i >= ETOT) return;
    int dst = (i < E) ? ei[E + i] : (i - E);
    atomicAdd(&deg[dst], 1);
}

// block scans 1024 elements (256 threads x 4)
__global__ void k_scan1(const int* __restrict__ deg, int* __restrict__ rowptr,
                        int* __restrict__ bsums, int n) {
    __shared__ int lds[256];
    int tid = threadIdx.x;
    int base = blockIdx.x * 1024 + tid * 4;
    int v[4];
    int tsum = 0;
#pragma unroll
    for (int j = 0; j < 4; ++j) {
        v[j] = (base + j < n) ? deg[base + j] : 0;
        tsum += v[j];
    }
    lds[tid] = tsum;
    __syncthreads();
    for (int d = 1; d < 256; d <<= 1) {
        int t = (tid >= d) ? lds[tid - d] : 0;
        __syncthreads();
        lds[tid] += t;
        __syncthreads();
    }
    int run = lds[tid] - tsum;  // exclusive prefix of this thread's chunk
#pragma unroll
    for (int j = 0; j < 4; ++j) {
        if (base + j < n) rowptr[base + j] = run;
        run += v[j];
    }
    if (tid == 255) bsums[blockIdx.x] = lds[255];
}

__global__ void k_scan2(int* __restrict__ bsums, int* __restrict__ rowptr_last, int nb) {
    __shared__ int lds[256];
    int tid = threadIdx.x;
    int v = (tid < nb) ? bsums[tid] : 0;
    lds[tid] = v;
    __syncthreads();
    for (int d = 1; d < 256; d <<= 1) {
        int t = (tid >= d) ? lds[tid - d] : 0;
        __syncthreads();
        lds[tid] += t;
        __syncthreads();
    }
    if (tid < nb) bsums[tid] = lds[tid] - v;    // exclusive
    if (tid == nb - 1) *rowptr_last = lds[tid]; // total = ETOT
}

__global__ void k_scan3(int* __restrict__ rowptr, const int* __restrict__ bsums,
                        int* __restrict__ cursor, int n) {
    int i = blockIdx.x * 256 + threadIdx.x;
    if (i >= n) return;
    int r = rowptr[i] + bsums[i >> 10];
    rowptr[i] = r;
    cursor[i] = r;
}

__global__ void k_scatter(const int* __restrict__ ei, int E, int ETOT,
                          int* __restrict__ cursor, int* __restrict__ ssrc) {
    int i = blockIdx.x * 256 + threadIdx.x;
    if (i >= ETOT) return;
    int src, dst;
    if (i < E) { src = ei[i]; dst = ei[E + i]; }
    else       { src = i - E; dst = i - E; }
    int pos = atomicAdd(&cursor[dst], 1);
    ssrc[pos] = src;
}

// ------------------------------ GEMM ---------------------------------------
// xp[N][OUT] = X[N][128] @ W[128][OUT], fp32. 32 rows per block, 256 threads.
template <int OUT>
__global__ __launch_bounds__(256) void k_gemm(const float* __restrict__ X,
                                              const float* __restrict__ W,
                                              float* __restrict__ XP, int N) {
    constexpr int IN = 128;
    constexpr int ROWS = 32;
    constexpr int COLV = OUT / 4;      // float4 columns (32 or 16)
    constexpr int RGRP = 256 / COLV;   // row groups (8 or 16)
    constexpr int RT = ROWS / RGRP;    // rows per thread (4 or 2)
    __shared__ float xs[ROWS][IN];
    const int tid = threadIdx.x;
    const int row0 = blockIdx.x * ROWS;

    // cooperative X tile load: 1024 float4s
    {
        const float4* Xv = (const float4*)(X + (size_t)row0 * IN);
        float4* xsv = (float4*)&xs[0][0];
#pragma unroll
        for (int j = 0; j < (ROWS * IN / 4) / 256; ++j)
            xsv[tid + j * 256] = Xv[tid + j * 256];
    }
    __syncthreads();

    const int cg = tid % COLV;
    const int rg = tid / COLV;
    float4 acc[RT];
#pragma unroll
    for (int r = 0; r < RT; ++r) acc[r] = make_float4(0.f, 0.f, 0.f, 0.f);

    const float4* Wv = (const float4*)W;  // [IN][COLV]
    for (int k0 = 0; k0 < IN; k0 += 4) {
        float4 w0 = Wv[(k0 + 0) * COLV + cg];
        float4 w1 = Wv[(k0 + 1) * COLV + cg];
        float4 w2 = Wv[(k0 + 2) * COLV + cg];
        float4 w3 = Wv[(k0 + 3) * COLV + cg];
#pragma unroll
        for (int r = 0; r < RT; ++r) {
            int rr = rg * RT + r;
            float4 xv = *(const float4*)&xs[rr][k0];
            acc[r].x += xv.x * w0.x + xv.y * w1.x + xv.z * w2.x + xv.w * w3.x;
            acc[r].y += xv.x * w0.y + xv.y * w1.y + xv.z * w2.y + xv.w * w3.y;
            acc[r].z += xv.x * w0.z + xv.y * w1.z + xv.z * w2.z + xv.w * w3.z;
            acc[r].w += xv.x * w0.w + xv.y * w1.w + xv.z * w2.w + xv.w * w3.w;
        }
    }
#pragma unroll
    for (int r = 0; r < RT; ++r) {
        int rr = row0 + rg * RT + r;
        ((float4*)(XP + (size_t)rr * OUT))[cg] = acc[r];
    }
}

// --------------------------- attention logits -------------------------------
// al_s[n][h] = sum_c xp[n][h*C+c]*a_src[h][c]  (a_* flat over OUT)
template <int OUT, int C>
__global__ __launch_bounds__(256) void k_al(const float* __restrict__ xp,
                                            const float* __restrict__ a_src,
                                            const float* __restrict__ a_dst,
                                            float* __restrict__ al_s,
                                            float* __restrict__ al_d, int N) {
    constexpr int H = OUT / C;
    int t = blockIdx.x * 256 + threadIdx.x;
    int node = t / OUT;
    int c = t % OUT;
    if (node >= N) return;
    float v = xp[(size_t)node * OUT + c];
    float ps = v * a_src[c];
    float pd = v * a_dst[c];
#pragma unroll
    for (int o = C / 2; o >= 1; o >>= 1) {
        ps += __shfl_xor(ps, o);
        pd += __shfl_xor(pd, o);
    }
    if ((c & (C - 1)) == 0) {
        int h = c / C;
        al_s[(size_t)node * H + h] = ps;
        al_d[(size_t)node * H + h] = pd;
    }
}

// --------------------------- softmax + aggregate ----------------------------
// one wave (64 lanes) per node; two passes over its incoming edges.
template <int OUT, int H, bool ELU>
__global__ __launch_bounds__(256) void k_agg(const float* __restrict__ xp,
                                             const float* __restrict__ al_s,
                                             const float* __restrict__ al_d,
                                             const int* __restrict__ rowptr,
                                             const int* __restrict__ ssrc,
                                             const float* __restrict__ bias,
                                             float* __restrict__ out, int N) {
    constexpr int C = OUT / H;
    constexpr int CPL = OUT / 64;  // channels per lane (2 or 1)
    const int wid = threadIdx.x >> 6;
    const int lane = threadIdx.x & 63;
    const int node = blockIdx.x * 4 + wid;
    if (node >= N) return;
    const int rs = rowptr[node];
    const int re = rowptr[node + 1];

    float ad[H];
    if constexpr (H == 4) {
        float4 t = *(const float4*)(al_d + (size_t)node * 4);
        ad[0] = t.x; ad[1] = t.y; ad[2] = t.z; ad[3] = t.w;
    } else {
        ad[0] = al_d[node];
    }

    // pass 1: per-head max over edges (lanes stride the edge list)
    float m[H];
#pragma unroll
    for (int h = 0; h < H; ++h) m[h] = -INFINITY;
    for (int i = rs + lane; i < re; i += 64) {
        int s = ssrc[i];
        if constexpr (H == 4) {
            float4 as = *(const float4*)(al_s + (size_t)s * 4);
            float e0 = as.x + ad[0]; e0 = e0 > 0.f ? e0 : 0.2f * e0;
            float e1 = as.y + ad[1]; e1 = e1 > 0.f ? e1 : 0.2f * e1;
            float e2 = as.z + ad[2]; e2 = e2 > 0.f ? e2 : 0.2f * e2;
            float e3 = as.w + ad[3]; e3 = e3 > 0.f ? e3 : 0.2f * e3;
            m[0] = fmaxf(m[0], e0); m[1] = fmaxf(m[1], e1);
            m[2] = fmaxf(m[2], e2); m[3] = fmaxf(m[3], e3);
        } else {
            float e = al_s[s] + ad[0];
            e = e > 0.f ? e : 0.2f * e;
            m[0] = fmaxf(m[0], e);
        }
    }
#pragma unroll
    for (int h = 0; h < H; ++h)
#pragma unroll
        for (int o = 32; o >= 1; o >>= 1) m[h] = fmaxf(m[h], __shfl_xor(m[h], o));

    // pass 2: all lanes walk all edges; each lane owns CPL channels
    const int c0 = lane * CPL;
    const int hd = c0 / C;
    const float adh = ad[hd];
    const float mh = m[hd];
    float ssum = 0.f;
    float acc[CPL];
#pragma unroll
    for (int j = 0; j < CPL; ++j) acc[j] = 0.f;

    for (int i = rs; i < re; ++i) {
        int s = ssrc[i];
        float e = al_s[(size_t)s * H + hd] + adh;
        e = e > 0.f ? e : 0.2f * e;
        float a = __expf(e - mh);
        ssum += a;
        const float* xr = xp + (size_t)s * OUT + c0;
        if constexpr (CPL == 2) {
            float2 v = *(const float2*)xr;
            acc[0] += a * v.x;
            acc[1] += a * v.y;
        } else {
            acc[0] += a * xr[0];
        }
    }

    float inv = 1.f / (ssum + 1e-16f);
#pragma unroll
    for (int j = 0; j < CPL; ++j) {
        float o = acc[j] * inv + bias[c0 + j];
        if constexpr (ELU) o = o > 0.f ? o : (__expf(o) - 1.f);
        out[(size_t)node * OUT + c0 + j] = o;
    }
}

// ------------------------------ launch --------------------------------------

extern "C" void kernel_launch(void* const* d_in, const int* in_sizes, int n_in,
                              void* d_out, int out_size, void* d_ws, size_t ws_size,
                              hipStream_t stream) {
    const int N = N_NODES;
    const float* x     = (const float*)d_in[0];
    const int*   ei    = (const int*)d_in[1];
    const float* W0    = (const float*)d_in[2];
    const float* as0   = (const float*)d_in[3];
    const float* ad0   = (const float*)d_in[4];
    const float* b0    = (const float*)d_in[5];
    const float* W1    = (const float*)d_in[6];
    const float* as1   = (const float*)d_in[7];
    const float* ad1   = (const float*)d_in[8];
    const float* b1    = (const float*)d_in[9];
    const float* W2    = (const float*)d_in[10];
    const float* as2   = (const float*)d_in[11];
    const float* ad2   = (const float*)d_in[12];
    const float* b2    = (const float*)d_in[13];
    float* out = (float*)d_out;

    const int E = in_sizes[1] / 2;
    const int ETOT = E + N;

    // workspace carve (256B aligned)
    char* p = (char*)d_ws;
    auto alloc = [&](size_t bytes) {
        void* r = (void*)p;
        p += (bytes + 255) & ~(size_t)255;
        return r;
    };
    float* xp     = (float*)alloc((size_t)N * 128 * 4);
    float* hbuf   = (float*)alloc((size_t)N * 128 * 4);
    float* als    = (float*)alloc((size_t)N * 4 * 4);
    float* ald    = (float*)alloc((size_t)N * 4 * 4);
    int*   deg    = (int*)alloc((size_t)N * 4);
    int*   rowptr = (int*)alloc((size_t)(N + 1) * 4);
    int*   cursor = (int*)alloc((size_t)N * 4);
    int*   bsums  = (int*)alloc(1024);
    int*   ssrc   = (int*)alloc((size_t)ETOT * 4);

    // ---- CSR build ----
    hipMemsetAsync(deg, 0, (size_t)N * 4, stream);
    k_hist<<<(ETOT + 255) / 256, 256, 0, stream>>>(ei, E, ETOT, deg);
    const int NB = (N + 1023) / 1024;  // 98 (<=256)
    k_scan1<<<NB, 256, 0, stream>>>(deg, rowptr, bsums, N);
    k_scan2<<<1, 256, 0, stream>>>(bsums, rowptr + N, NB);
    k_scan3<<<(N + 255) / 256, 256, 0, stream>>>(rowptr, bsums, cursor, N);
    k_scatter<<<(ETOT + 255) / 256, 256, 0, stream>>>(ei, E, ETOT, cursor, ssrc);

    const int gGemm = (N + 31) / 32;
    const int gAgg  = (N + 3) / 4;

    // ---- layer 0: 128 -> 4x32, ELU ----
    k_gemm<128><<<gGemm, 256, 0, stream>>>(x, W0, xp, N);
    k_al<128, 32><<<(N * 128 + 255) / 256, 256, 0, stream>>>(xp, as0, ad0, als, ald, N);
    k_agg<128, 4, true><<<gAgg, 256, 0, stream>>>(xp, als, ald, rowptr, ssrc, b0, hbuf, N);

    // ---- layer 1: 128 -> 4x32, ELU ----
    k_gemm<128><<<gGemm, 256, 0, stream>>>(hbuf, W1, xp, N);
    k_al<128, 32><<<(N * 128 + 255) / 256, 256, 0, stream>>>(xp, as1, ad1, als, ald, N);
    k_agg<128, 4, true><<<gAgg, 256, 0, stream>>>(xp, als, ald, rowptr, ssrc, b1, hbuf, N);

    // ---- layer 2: 128 -> 1x64, no ELU, mean over 1 head = identity ----
    k_gemm<64><<<gGemm, 256, 0, stream>>>(hbuf, W2, xp, N);
    k_al<64, 64><<<(N * 64 + 255) / 256, 256, 0, stream>>>(xp, as2, ad2, als, ald, N);
    k_agg<64, 1, false><<<gAgg, 256, 0, stream>>>(xp, als, ald, rowptr, ssrc, b2, out, N);
}

// Round 2
// 760.858 us; speedup vs baseline: 1.3384x; 1.3384x over previous
//
#include <hip/hip_runtime.h>
#include <math.h>

// ---------------------------------------------------------------------------
// GAT (3-layer PyG GATConv, eval) on MI355X.
//   CSR build: hist(deg) -> scan -> scatter (sorted by dst, self-loops)
//   per layer: k_gemm (xp = h @ W, fused attention-logit epilogue),
//              k_agg (segment softmax + weighted aggregation + bias + ELU)
// R2: k_agg pass-2 = half-wave per edge, 2-edge unroll (4 edges in flight);
//     k_al fused into k_gemm epilogue.
// ---------------------------------------------------------------------------

#define N_NODES 100000

// ------------------------------ CSR build ----------------------------------

__global__ void k_hist(const int* __restrict__ ei, int E, int ETOT, int* __restrict__ deg) {
    int i = blockIdx.x * 256 + threadIdx.x;
    if (i >= ETOT) return;
    int dst = (i < E) ? ei[E + i] : (i - E);
    atomicAdd(&deg[dst], 1);
}

// block scans 1024 elements (256 threads x 4)
__global__ void k_scan1(const int* __restrict__ deg, int* __restrict__ rowptr,
                        int* __restrict__ bsums, int n) {
    __shared__ int lds[256];
    int tid = threadIdx.x;
    int base = blockIdx.x * 1024 + tid * 4;
    int v[4];
    int tsum = 0;
#pragma unroll
    for (int j = 0; j < 4; ++j) {
        v[j] = (base + j < n) ? deg[base + j] : 0;
        tsum += v[j];
    }
    lds[tid] = tsum;
    __syncthreads();
    for (int d = 1; d < 256; d <<= 1) {
        int t = (tid >= d) ? lds[tid - d] : 0;
        __syncthreads();
        lds[tid] += t;
        __syncthreads();
    }
    int run = lds[tid] - tsum;  // exclusive prefix of this thread's chunk
#pragma unroll
    for (int j = 0; j < 4; ++j) {
        if (base + j < n) rowptr[base + j] = run;
        run += v[j];
    }
    if (tid == 255) bsums[blockIdx.x] = lds[255];
}

__global__ void k_scan2(int* __restrict__ bsums, int* __restrict__ rowptr_last, int nb) {
    __shared__ int lds[256];
    int tid = threadIdx.x;
    int v = (tid < nb) ? bsums[tid] : 0;
    lds[tid] = v;
    __syncthreads();
    for (int d = 1; d < 256; d <<= 1) {
        int t = (tid >= d) ? lds[tid - d] : 0;
        __syncthreads();
        lds[tid] += t;
        __syncthreads();
    }
    if (tid < nb) bsums[tid] = lds[tid] - v;    // exclusive
    if (tid == nb - 1) *rowptr_last = lds[tid]; // total = ETOT
}

__global__ void k_scan3(int* __restrict__ rowptr, const int* __restrict__ bsums,
                        int* __restrict__ cursor, int n) {
    int i = blockIdx.x * 256 + threadIdx.x;
    if (i >= n) return;
    int r = rowptr[i] + bsums[i >> 10];
    rowptr[i] = r;
    cursor[i] = r;
}

__global__ void k_scatter(const int* __restrict__ ei, int E, int ETOT,
                          int* __restrict__ cursor, int* __restrict__ ssrc) {
    int i = blockIdx.x * 256 + threadIdx.x;
    if (i >= ETOT) return;
    int src, dst;
    if (i < E) { src = ei[i]; dst = ei[E + i]; }
    else       { src = i - E; dst = i - E; }
    int pos = atomicAdd(&cursor[dst], 1);
    ssrc[pos] = src;
}

// ------------------------------ GEMM + logits -------------------------------
// xp[N][OUT] = X[N][128] @ W[128][OUT], fp32; epilogue computes
// al_s[n][h] = dot(xp[n, head h], a_src[h]) and same for al_d via shfl reduce.
template <int OUT, int H>
__global__ __launch_bounds__(256) void k_gemm(const float* __restrict__ X,
                                              const float* __restrict__ W,
                                              const float* __restrict__ a_src,
                                              const float* __restrict__ a_dst,
                                              float* __restrict__ XP,
                                              float* __restrict__ al_s,
                                              float* __restrict__ al_d, int N) {
    constexpr int IN = 128;
    constexpr int ROWS = 32;
    constexpr int COLV = OUT / 4;      // float4 columns (32 or 16)
    constexpr int RGRP = 256 / COLV;   // row groups (8 or 16)
    constexpr int RT = ROWS / RGRP;    // rows per thread (4 or 2)
    constexpr int C = OUT / H;         // channels per head
    constexpr int CGH = C / 4;         // col-groups per head (8 or 16)
    __shared__ float xs[ROWS][IN];
    const int tid = threadIdx.x;
    const int row0 = blockIdx.x * ROWS;

    // cooperative X tile load: 1024 float4s
    {
        const float4* Xv = (const float4*)(X + (size_t)row0 * IN);
        float4* xsv = (float4*)&xs[0][0];
#pragma unroll
        for (int j = 0; j < (ROWS * IN / 4) / 256; ++j)
            xsv[tid + j * 256] = Xv[tid + j * 256];
    }
    __syncthreads();

    const int cg = tid % COLV;
    const int rg = tid / COLV;
    float4 acc[RT];
#pragma unroll
    for (int r = 0; r < RT; ++r) acc[r] = make_float4(0.f, 0.f, 0.f, 0.f);

    const float4* Wv = (const float4*)W;  // [IN][COLV]
    for (int k0 = 0; k0 < IN; k0 += 4) {
        float4 w0 = Wv[(k0 + 0) * COLV + cg];
        float4 w1 = Wv[(k0 + 1) * COLV + cg];
        float4 w2 = Wv[(k0 + 2) * COLV + cg];
        float4 w3 = Wv[(k0 + 3) * COLV + cg];
#pragma unroll
        for (int r = 0; r < RT; ++r) {
            int rr = rg * RT + r;
            float4 xv = *(const float4*)&xs[rr][k0];
            acc[r].x += xv.x * w0.x + xv.y * w1.x + xv.z * w2.x + xv.w * w3.x;
            acc[r].y += xv.x * w0.y + xv.y * w1.y + xv.z * w2.y + xv.w * w3.y;
            acc[r].z += xv.x * w0.z + xv.y * w1.z + xv.z * w2.z + xv.w * w3.z;
            acc[r].w += xv.x * w0.w + xv.y * w1.w + xv.z * w2.w + xv.w * w3.w;
        }
    }
#pragma unroll
    for (int r = 0; r < RT; ++r) {
        int rr = row0 + rg * RT + r;
        ((float4*)(XP + (size_t)rr * OUT))[cg] = acc[r];
    }

    // fused attention-logit epilogue: per-head dot + shfl reduction.
    // threads with the same rg are CGH-aligned consecutive lanes per head.
    const float4 asv = ((const float4*)a_src)[cg];
    const float4 adv = ((const float4*)a_dst)[cg];
#pragma unroll
    for (int r = 0; r < RT; ++r) {
        float ps = acc[r].x * asv.x + acc[r].y * asv.y + acc[r].z * asv.z + acc[r].w * asv.w;
        float pd = acc[r].x * adv.x + acc[r].y * adv.y + acc[r].z * adv.z + acc[r].w * adv.w;
#pragma unroll
        for (int o = CGH / 2; o >= 1; o >>= 1) {
            ps += __shfl_xor(ps, o);
            pd += __shfl_xor(pd, o);
        }
        if ((cg & (CGH - 1)) == 0) {
            int rr = row0 + rg * RT + r;
            int h = cg / CGH;
            al_s[(size_t)rr * H + h] = ps;
            al_d[(size_t)rr * H + h] = pd;
        }
    }
}

// --------------------------- softmax + aggregate ----------------------------
// one wave per node. pass 1: strided per-head max. pass 2: half-wave per
// edge (32 lanes x CPL channels), 2-edge unroll -> 4 edges in flight.
template <int OUT, int H, bool ELU>
__global__ __launch_bounds__(256) void k_agg(const float* __restrict__ xp,
                                             const float* __restrict__ al_s,
                                             const float* __restrict__ al_d,
                                             const int* __restrict__ rowptr,
                                             const int* __restrict__ ssrc,
                                             const float* __restrict__ bias,
                                             float* __restrict__ out, int N) {
    constexpr int C = OUT / H;
    constexpr int CPL = OUT / 32;  // channels per lane in a half-wave (4 or 2)
    const int wid = threadIdx.x >> 6;
    const int lane = threadIdx.x & 63;
    const int half = lane >> 5;
    const int l5 = lane & 31;
    const int node = blockIdx.x * 4 + wid;
    if (node >= N) return;
    const int rs = rowptr[node];
    const int re = rowptr[node + 1];

    float ad[H];
    if constexpr (H == 4) {
        float4 t = *(const float4*)(al_d + (size_t)node * 4);
        ad[0] = t.x; ad[1] = t.y; ad[2] = t.z; ad[3] = t.w;
    } else {
        ad[0] = al_d[node];
    }

    // pass 1: per-head max over edges (full wave, lanes stride the edge list)
    float m[H];
#pragma unroll
    for (int h = 0; h < H; ++h) m[h] = -INFINITY;
    for (int i = rs + lane; i < re; i += 64) {
        int s = ssrc[i];
        if constexpr (H == 4) {
            float4 as = *(const float4*)(al_s + (size_t)s * 4);
            float e0 = as.x + ad[0]; e0 = e0 > 0.f ? e0 : 0.2f * e0;
            float e1 = as.y + ad[1]; e1 = e1 > 0.f ? e1 : 0.2f * e1;
            float e2 = as.z + ad[2]; e2 = e2 > 0.f ? e2 : 0.2f * e2;
            float e3 = as.w + ad[3]; e3 = e3 > 0.f ? e3 : 0.2f * e3;
            m[0] = fmaxf(m[0], e0); m[1] = fmaxf(m[1], e1);
            m[2] = fmaxf(m[2], e2); m[3] = fmaxf(m[3], e3);
        } else {
            float e = al_s[s] + ad[0];
            e = e > 0.f ? e : 0.2f * e;
            m[0] = fmaxf(m[0], e);
        }
    }
#pragma unroll
    for (int h = 0; h < H; ++h)
#pragma unroll
        for (int o = 32; o >= 1; o >>= 1) m[h] = fmaxf(m[h], __shfl_xor(m[h], o));

    // pass 2: half-wave per edge; each lane owns CPL channels of the output.
    const int c0 = l5 * CPL;
    const int hd = c0 / C;
    const float adh = ad[hd];
    const float mh = m[hd];
    float ssum = 0.f;
    float acc[CPL];
#pragma unroll
    for (int j = 0; j < CPL; ++j) acc[j] = 0.f;

    int i = rs;
    // main: 4 edges per trip (this half handles i+half and i+half+2)
    for (; i + 4 <= re; i += 4) {
        int sA = ssrc[i + half];
        int sB = ssrc[i + half + 2];
        float eA = al_s[(size_t)sA * H + hd] + adh; eA = eA > 0.f ? eA : 0.2f * eA;
        float eB = al_s[(size_t)sB * H + hd] + adh; eB = eB > 0.f ? eB : 0.2f * eB;
        float aA = __expf(eA - mh);
        float aB = __expf(eB - mh);
        ssum += aA + aB;
        const float* xA = xp + (size_t)sA * OUT + c0;
        const float* xB = xp + (size_t)sB * OUT + c0;
        if constexpr (CPL == 4) {
            float4 vA = *(const float4*)xA;
            float4 vB = *(const float4*)xB;
            acc[0] += aA * vA.x + aB * vB.x;
            acc[1] += aA * vA.y + aB * vB.y;
            acc[2] += aA * vA.z + aB * vB.z;
            acc[3] += aA * vA.w + aB * vB.w;
        } else {
            float2 vA = *(const float2*)xA;
            float2 vB = *(const float2*)xB;
            acc[0] += aA * vA.x + aB * vB.x;
            acc[1] += aA * vA.y + aB * vB.y;
        }
    }
    // tail: up to 3 edges, per-half predicated
    for (; i + half < re; i += 2) {
        int s = ssrc[i + half];
        float e = al_s[(size_t)s * H + hd] + adh; e = e > 0.f ? e : 0.2f * e;
        float a = __expf(e - mh);
        ssum += a;
        const float* xr = xp + (size_t)s * OUT + c0;
        if constexpr (CPL == 4) {
            float4 v = *(const float4*)xr;
            acc[0] += a * v.x; acc[1] += a * v.y;
            acc[2] += a * v.z; acc[3] += a * v.w;
        } else {
            float2 v = *(const float2*)xr;
            acc[0] += a * v.x; acc[1] += a * v.y;
        }
    }

    // combine the two halves
    ssum += __shfl_xor(ssum, 32);
#pragma unroll
    for (int j = 0; j < CPL; ++j) acc[j] += __shfl_xor(acc[j], 32);

    if (half == 0) {
        float inv = 1.f / (ssum + 1e-16f);
        float o[CPL];
#pragma unroll
        for (int j = 0; j < CPL; ++j) {
            o[j] = acc[j] * inv + bias[c0 + j];
            if constexpr (ELU) o[j] = o[j] > 0.f ? o[j] : (__expf(o[j]) - 1.f);
        }
        if constexpr (CPL == 4) {
            *(float4*)(out + (size_t)node * OUT + c0) = make_float4(o[0], o[1], o[2], o[3]);
        } else {
            *(float2*)(out + (size_t)node * OUT + c0) = make_float2(o[0], o[1]);
        }
    }
}

// ------------------------------ launch --------------------------------------

extern "C" void kernel_launch(void* const* d_in, const int* in_sizes, int n_in,
                              void* d_out, int out_size, void* d_ws, size_t ws_size,
                              hipStream_t stream) {
    const int N = N_NODES;
    const float* x     = (const float*)d_in[0];
    const int*   ei    = (const int*)d_in[1];
    const float* W0    = (const float*)d_in[2];
    const float* as0   = (const float*)d_in[3];
    const float* ad0   = (const float*)d_in[4];
    const float* b0    = (const float*)d_in[5];
    const float* W1    = (const float*)d_in[6];
    const float* as1   = (const float*)d_in[7];
    const float* ad1   = (const float*)d_in[8];
    const float* b1    = (const float*)d_in[9];
    const float* W2    = (const float*)d_in[10];
    const float* as2   = (const float*)d_in[11];
    const float* ad2   = (const float*)d_in[12];
    const float* b2    = (const float*)d_in[13];
    float* out = (float*)d_out;

    const int E = in_sizes[1] / 2;
    const int ETOT = E + N;

    // workspace carve (256B aligned)
    char* p = (char*)d_ws;
    auto alloc = [&](size_t bytes) {
        void* r = (void*)p;
        p += (bytes + 255) & ~(size_t)255;
        return r;
    };
    float* xp     = (float*)alloc((size_t)N * 128 * 4);
    float* hbuf   = (float*)alloc((size_t)N * 128 * 4);
    float* als    = (float*)alloc((size_t)N * 4 * 4);
    float* ald    = (float*)alloc((size_t)N * 4 * 4);
    int*   deg    = (int*)alloc((size_t)N * 4);
    int*   rowptr = (int*)alloc((size_t)(N + 1) * 4);
    int*   cursor = (int*)alloc((size_t)N * 4);
    int*   bsums  = (int*)alloc(1024);
    int*   ssrc   = (int*)alloc((size_t)ETOT * 4);

    // ---- CSR build ----
    hipMemsetAsync(deg, 0, (size_t)N * 4, stream);
    k_hist<<<(ETOT + 255) / 256, 256, 0, stream>>>(ei, E, ETOT, deg);
    const int NB = (N + 1023) / 1024;  // 98 (<=256)
    k_scan1<<<NB, 256, 0, stream>>>(deg, rowptr, bsums, N);
    k_scan2<<<1, 256, 0, stream>>>(bsums, rowptr + N, NB);
    k_scan3<<<(N + 255) / 256, 256, 0, stream>>>(rowptr, bsums, cursor, N);
    k_scatter<<<(ETOT + 255) / 256, 256, 0, stream>>>(ei, E, ETOT, cursor, ssrc);

    const int gGemm = (N + 31) / 32;
    const int gAgg  = (N + 3) / 4;

    // ---- layer 0: 128 -> 4x32, ELU ----
    k_gemm<128, 4><<<gGemm, 256, 0, stream>>>(x, W0, as0, ad0, xp, als, ald, N);
    k_agg<128, 4, true><<<gAgg, 256, 0, stream>>>(xp, als, ald, rowptr, ssrc, b0, hbuf, N);

    // ---- layer 1: 128 -> 4x32, ELU ----
    k_gemm<128, 4><<<gGemm, 256, 0, stream>>>(hbuf, W1, as1, ad1, xp, als, ald, N);
    k_agg<128, 4, true><<<gAgg, 256, 0, stream>>>(xp, als, ald, rowptr, ssrc, b1, hbuf, N);

    // ---- layer 2: 128 -> 1x64, no ELU, mean over 1 head = identity ----
    k_gemm<64, 1><<<gGemm, 256, 0, stream>>>(hbuf, W2, as2, ad2, xp, als, ald, N);
    k_agg<64, 1, false><<<gAgg, 256, 0, stream>>>(xp, als, ald, rowptr, ssrc, b2, out, N);
}

// Round 3
// 608.059 us; speedup vs baseline: 1.6748x; 1.2513x over previous
//
#include <hip/hip_runtime.h>
#include <math.h>

// ---------------------------------------------------------------------------
// GAT (3-layer PyG GATConv, eval) on MI355X.
//   CSR build: hist(deg) -> scan -> scatter (sorted by dst, self-loops)
//   per layer: k_gemm (xp = h @ W -> fp16, fused attention-logit epilogue),
//              k_agg (single-pass segment softmax + aggregation + bias + ELU)
// R3: xp stored fp16 (halves gather bytes); quarter-wave per edge, 8 edges
//     in flight; max-pass dropped (logits tiny, exp can't overflow).
// ---------------------------------------------------------------------------

#define N_NODES 100000

typedef __attribute__((ext_vector_type(4))) _Float16 half4;
typedef __attribute__((ext_vector_type(8))) _Float16 half8;

// ------------------------------ CSR build ----------------------------------

__global__ void k_hist(const int* __restrict__ ei, int E, int ETOT, int* __restrict__ deg) {
    int i = blockIdx.x * 256 + threadIdx.x;
    if (i >= ETOT) return;
    int dst = (i < E) ? ei[E + i] : (i - E);
    atomicAdd(&deg[dst], 1);
}

// block scans 1024 elements (256 threads x 4)
__global__ void k_scan1(const int* __restrict__ deg, int* __restrict__ rowptr,
                        int* __restrict__ bsums, int n) {
    __shared__ int lds[256];
    int tid = threadIdx.x;
    int base = blockIdx.x * 1024 + tid * 4;
    int v[4];
    int tsum = 0;
#pragma unroll
    for (int j = 0; j < 4; ++j) {
        v[j] = (base + j < n) ? deg[base + j] : 0;
        tsum += v[j];
    }
    lds[tid] = tsum;
    __syncthreads();
    for (int d = 1; d < 256; d <<= 1) {
        int t = (tid >= d) ? lds[tid - d] : 0;
        __syncthreads();
        lds[tid] += t;
        __syncthreads();
    }
    int run = lds[tid] - tsum;  // exclusive prefix of this thread's chunk
#pragma unroll
    for (int j = 0; j < 4; ++j) {
        if (base + j < n) rowptr[base + j] = run;
        run += v[j];
    }
    if (tid == 255) bsums[blockIdx.x] = lds[255];
}

__global__ void k_scan2(int* __restrict__ bsums, int* __restrict__ rowptr_last, int nb) {
    __shared__ int lds[256];
    int tid = threadIdx.x;
    int v = (tid < nb) ? bsums[tid] : 0;
    lds[tid] = v;
    __syncthreads();
    for (int d = 1; d < 256; d <<= 1) {
        int t = (tid >= d) ? lds[tid - d] : 0;
        __syncthreads();
        lds[tid] += t;
        __syncthreads();
    }
    if (tid < nb) bsums[tid] = lds[tid] - v;    // exclusive
    if (tid == nb - 1) *rowptr_last = lds[tid]; // total = ETOT
}

__global__ void k_scan3(int* __restrict__ rowptr, const int* __restrict__ bsums,
                        int* __restrict__ cursor, int n) {
    int i = blockIdx.x * 256 + threadIdx.x;
    if (i >= n) return;
    int r = rowptr[i] + bsums[i >> 10];
    rowptr[i] = r;
    cursor[i] = r;
}

__global__ void k_scatter(const int* __restrict__ ei, int E, int ETOT,
                          int* __restrict__ cursor, int* __restrict__ ssrc) {
    int i = blockIdx.x * 256 + threadIdx.x;
    if (i >= ETOT) return;
    int src, dst;
    if (i < E) { src = ei[i]; dst = ei[E + i]; }
    else       { src = i - E; dst = i - E; }
    int pos = atomicAdd(&cursor[dst], 1);
    ssrc[pos] = src;
}

// ------------------------------ GEMM + logits -------------------------------
// xp[N][OUT] = X[N][128] @ W[128][OUT] (stored fp16); epilogue computes
// al_s[n][h] = dot(xp[n, head h], a_src[h]) (fp32 acc) and same for al_d.
template <int OUT, int H>
__global__ __launch_bounds__(256) void k_gemm(const float* __restrict__ X,
                                              const float* __restrict__ W,
                                              const float* __restrict__ a_src,
                                              const float* __restrict__ a_dst,
                                              _Float16* __restrict__ XP,
                                              float* __restrict__ al_s,
                                              float* __restrict__ al_d, int N) {
    constexpr int IN = 128;
    constexpr int ROWS = 32;
    constexpr int COLV = OUT / 4;      // float4 columns (32 or 16)
    constexpr int RGRP = 256 / COLV;   // row groups (8 or 16)
    constexpr int RT = ROWS / RGRP;    // rows per thread (4 or 2)
    constexpr int C = OUT / H;         // channels per head
    constexpr int CGH = C / 4;         // col-groups per head (8 or 16)
    __shared__ float xs[ROWS][IN];
    const int tid = threadIdx.x;
    const int row0 = blockIdx.x * ROWS;

    // cooperative X tile load: 1024 float4s
    {
        const float4* Xv = (const float4*)(X + (size_t)row0 * IN);
        float4* xsv = (float4*)&xs[0][0];
#pragma unroll
        for (int j = 0; j < (ROWS * IN / 4) / 256; ++j)
            xsv[tid + j * 256] = Xv[tid + j * 256];
    }
    __syncthreads();

    const int cg = tid % COLV;
    const int rg = tid / COLV;
    float4 acc[RT];
#pragma unroll
    for (int r = 0; r < RT; ++r) acc[r] = make_float4(0.f, 0.f, 0.f, 0.f);

    const float4* Wv = (const float4*)W;  // [IN][COLV]
    for (int k0 = 0; k0 < IN; k0 += 4) {
        float4 w0 = Wv[(k0 + 0) * COLV + cg];
        float4 w1 = Wv[(k0 + 1) * COLV + cg];
        float4 w2 = Wv[(k0 + 2) * COLV + cg];
        float4 w3 = Wv[(k0 + 3) * COLV + cg];
#pragma unroll
        for (int r = 0; r < RT; ++r) {
            int rr = rg * RT + r;
            float4 xv = *(const float4*)&xs[rr][k0];
            acc[r].x += xv.x * w0.x + xv.y * w1.x + xv.z * w2.x + xv.w * w3.x;
            acc[r].y += xv.x * w0.y + xv.y * w1.y + xv.z * w2.y + xv.w * w3.y;
            acc[r].z += xv.x * w0.z + xv.y * w1.z + xv.z * w2.z + xv.w * w3.z;
            acc[r].w += xv.x * w0.w + xv.y * w1.w + xv.z * w2.w + xv.w * w3.w;
        }
    }
#pragma unroll
    for (int r = 0; r < RT; ++r) {
        int rr = row0 + rg * RT + r;
        half4 hv;
        hv[0] = (_Float16)acc[r].x; hv[1] = (_Float16)acc[r].y;
        hv[2] = (_Float16)acc[r].z; hv[3] = (_Float16)acc[r].w;
        *(half4*)(XP + (size_t)rr * OUT + cg * 4) = hv;
    }

    // fused attention-logit epilogue: per-head dot + shfl reduction.
    const float4 asv = ((const float4*)a_src)[cg];
    const float4 adv = ((const float4*)a_dst)[cg];
#pragma unroll
    for (int r = 0; r < RT; ++r) {
        float ps = acc[r].x * asv.x + acc[r].y * asv.y + acc[r].z * asv.z + acc[r].w * asv.w;
        float pd = acc[r].x * adv.x + acc[r].y * adv.y + acc[r].z * adv.z + acc[r].w * adv.w;
#pragma unroll
        for (int o = CGH / 2; o >= 1; o >>= 1) {
            ps += __shfl_xor(ps, o);
            pd += __shfl_xor(pd, o);
        }
        if ((cg & (CGH - 1)) == 0) {
            int rr = row0 + rg * RT + r;
            int h = cg / CGH;
            al_s[(size_t)rr * H + h] = ps;
            al_d[(size_t)rr * H + h] = pd;
        }
    }
}

// --------------------------- softmax + aggregate ----------------------------
// one wave per node, single pass (no max subtraction -- logits are O(5)).
// quarter-wave (16 lanes) per edge, 2-edge unroll -> 8 edges in flight.
template <int OUT, int H, bool ELU>
__global__ __launch_bounds__(256) void k_agg(const _Float16* __restrict__ xp,
                                             const float* __restrict__ al_s,
                                             const float* __restrict__ al_d,
                                             const int* __restrict__ rowptr,
                                             const int* __restrict__ ssrc,
                                             const float* __restrict__ bias,
                                             float* __restrict__ out, int N) {
    constexpr int C = OUT / H;
    constexpr int CPL = OUT / 16;  // fp16 channels per lane in a quarter (8 or 4)
    const int wid = threadIdx.x >> 6;
    const int lane = threadIdx.x & 63;
    const int qid = lane >> 4;   // quarter 0..3
    const int l4 = lane & 15;
    const int node = blockIdx.x * 4 + wid;
    if (node >= N) return;
    const int rs = rowptr[node];
    const int re = rowptr[node + 1];

    const int c0 = l4 * CPL;
    const int hd = c0 / C;
    const float adh = al_d[(size_t)node * H + hd];

    float ssum = 0.f;
    float acc[CPL];
#pragma unroll
    for (int j = 0; j < CPL; ++j) acc[j] = 0.f;

    int i = rs;
    // main: 8 edges per trip (this quarter handles i+qid and i+qid+4)
    for (; i + 8 <= re; i += 8) {
        int sA = ssrc[i + qid];
        int sB = ssrc[i + qid + 4];
        float eA = al_s[(size_t)sA * H + hd] + adh; eA = eA > 0.f ? eA : 0.2f * eA;
        float eB = al_s[(size_t)sB * H + hd] + adh; eB = eB > 0.f ? eB : 0.2f * eB;
        float aA = __expf(eA);
        float aB = __expf(eB);
        ssum += aA + aB;
        if constexpr (CPL == 8) {
            half8 vA = *(const half8*)(xp + (size_t)sA * OUT + c0);
            half8 vB = *(const half8*)(xp + (size_t)sB * OUT + c0);
#pragma unroll
            for (int j = 0; j < 8; ++j) acc[j] += aA * (float)vA[j] + aB * (float)vB[j];
        } else {
            half4 vA = *(const half4*)(xp + (size_t)sA * OUT + c0);
            half4 vB = *(const half4*)(xp + (size_t)sB * OUT + c0);
#pragma unroll
            for (int j = 0; j < 4; ++j) acc[j] += aA * (float)vA[j] + aB * (float)vB[j];
        }
    }
    // tail: up to 7 edges, one per quarter per trip
    for (; i + qid < re; i += 4) {
        int s = ssrc[i + qid];
        float e = al_s[(size_t)s * H + hd] + adh; e = e > 0.f ? e : 0.2f * e;
        float a = __expf(e);
        ssum += a;
        if constexpr (CPL == 8) {
            half8 v = *(const half8*)(xp + (size_t)s * OUT + c0);
#pragma unroll
            for (int j = 0; j < 8; ++j) acc[j] += a * (float)v[j];
        } else {
            half4 v = *(const half4*)(xp + (size_t)s * OUT + c0);
#pragma unroll
            for (int j = 0; j < 4; ++j) acc[j] += a * (float)v[j];
        }
    }

    // combine the four quarters
    ssum += __shfl_xor(ssum, 16);
    ssum += __shfl_xor(ssum, 32);
#pragma unroll
    for (int j = 0; j < CPL; ++j) {
        acc[j] += __shfl_xor(acc[j], 16);
        acc[j] += __shfl_xor(acc[j], 32);
    }

    if (qid == 0) {
        float inv = 1.f / (ssum + 1e-16f);
        float o[CPL];
#pragma unroll
        for (int j = 0; j < CPL; ++j) {
            o[j] = acc[j] * inv + bias[c0 + j];
            if constexpr (ELU) o[j] = o[j] > 0.f ? o[j] : (__expf(o[j]) - 1.f);
        }
        float* op = out + (size_t)node * OUT + c0;
        if constexpr (CPL == 8) {
            *(float4*)op = make_float4(o[0], o[1], o[2], o[3]);
            *(float4*)(op + 4) = make_float4(o[4], o[5], o[6], o[7]);
        } else {
            *(float4*)op = make_float4(o[0], o[1], o[2], o[3]);
        }
    }
}

// ------------------------------ launch --------------------------------------

extern "C" void kernel_launch(void* const* d_in, const int* in_sizes, int n_in,
                              void* d_out, int out_size, void* d_ws, size_t ws_size,
                              hipStream_t stream) {
    const int N = N_NODES;
    const float* x     = (const float*)d_in[0];
    const int*   ei    = (const int*)d_in[1];
    const float* W0    = (const float*)d_in[2];
    const float* as0   = (const float*)d_in[3];
    const float* ad0   = (const float*)d_in[4];
    const float* b0    = (const float*)d_in[5];
    const float* W1    = (const float*)d_in[6];
    const float* as1   = (const float*)d_in[7];
    const float* ad1   = (const float*)d_in[8];
    const float* b1    = (const float*)d_in[9];
    const float* W2    = (const float*)d_in[10];
    const float* as2   = (const float*)d_in[11];
    const float* ad2   = (const float*)d_in[12];
    const float* b2    = (const float*)d_in[13];
    float* out = (float*)d_out;

    const int E = in_sizes[1] / 2;
    const int ETOT = E + N;

    // workspace carve (256B aligned)
    char* p = (char*)d_ws;
    auto alloc = [&](size_t bytes) {
        void* r = (void*)p;
        p += (bytes + 255) & ~(size_t)255;
        return r;
    };
    _Float16* xp   = (_Float16*)alloc((size_t)N * 128 * 2);
    float* hbuf    = (float*)alloc((size_t)N * 128 * 4);
    float* als     = (float*)alloc((size_t)N * 4 * 4);
    float* ald     = (float*)alloc((size_t)N * 4 * 4);
    int*   deg     = (int*)alloc((size_t)N * 4);
    int*   rowptr  = (int*)alloc((size_t)(N + 1) * 4);
    int*   cursor  = (int*)alloc((size_t)N * 4);
    int*   bsums   = (int*)alloc(1024);
    int*   ssrc    = (int*)alloc((size_t)ETOT * 4);

    // ---- CSR build ----
    hipMemsetAsync(deg, 0, (size_t)N * 4, stream);
    k_hist<<<(ETOT + 255) / 256, 256, 0, stream>>>(ei, E, ETOT, deg);
    const int NB = (N + 1023) / 1024;  // 98 (<=256)
    k_scan1<<<NB, 256, 0, stream>>>(deg, rowptr, bsums, N);
    k_scan2<<<1, 256, 0, stream>>>(bsums, rowptr + N, NB);
    k_scan3<<<(N + 255) / 256, 256, 0, stream>>>(rowptr, bsums, cursor, N);
    k_scatter<<<(ETOT + 255) / 256, 256, 0, stream>>>(ei, E, ETOT, cursor, ssrc);

    const int gGemm = (N + 31) / 32;
    const int gAgg  = (N + 3) / 4;

    // ---- layer 0: 128 -> 4x32, ELU ----
    k_gemm<128, 4><<<gGemm, 256, 0, stream>>>(x, W0, as0, ad0, xp, als, ald, N);
    k_agg<128, 4, true><<<gAgg, 256, 0, stream>>>(xp, als, ald, rowptr, ssrc, b0, hbuf, N);

    // ---- layer 1: 128 -> 4x32, ELU ----
    k_gemm<128, 4><<<gGemm, 256, 0, stream>>>(hbuf, W1, as1, ad1, xp, als, ald, N);
    k_agg<128, 4, true><<<gAgg, 256, 0, stream>>>(xp, als, ald, rowptr, ssrc, b1, hbuf, N);

    // ---- layer 2: 128 -> 1x64, no ELU, mean over 1 head = identity ----
    k_gemm<64, 1><<<gGemm, 256, 0, stream>>>(hbuf, W2, as2, ad2, xp, als, ald, N);
    k_agg<64, 1, false><<<gAgg, 256, 0, stream>>>(xp, als, ald, rowptr, ssrc, b2, out, N);
}

// Round 4
// 469.973 us; speedup vs baseline: 2.1668x; 1.2938x over previous
//
#include <hip/hip_runtime.h>
#include <math.h>

// ---------------------------------------------------------------------------
// GAT (3-layer PyG GATConv, eval) on MI355X.
//   CSR build (R4): two-level bucket sort, no random scatter --
//     k_bcount (bucket histogram) -> k_bscan (bases) ->
//     k_bplace (block-binned coalesced runs of packed (src,dstLocal)) ->
//     k_bfinal (per-bucket exact sort, emits rowptr + ssrc, coalesced)
//   per layer: k_gemm (xp = h @ W -> fp16, fused attention-logit epilogue),
//              k_agg (single-pass segment softmax + aggregation + bias + ELU)
// ---------------------------------------------------------------------------

#define N_NODES 100000
#define NBUCK ((N_NODES + 255) / 256)   // 391 buckets of 256 nodes

typedef __attribute__((ext_vector_type(4))) _Float16 half4;
typedef __attribute__((ext_vector_type(8))) _Float16 half8;

// ------------------------------ CSR build ----------------------------------

// per-block LDS histogram over dst buckets
__global__ __launch_bounds__(256) void k_bcount(const int* __restrict__ ei, int E, int ETOT,
                                                int* __restrict__ bucketCnt) {
    __shared__ int h[NBUCK];
    for (int b = threadIdx.x; b < NBUCK; b += 256) h[b] = 0;
    __syncthreads();
    const int base = blockIdx.x * 4096;
#pragma unroll
    for (int j = 0; j < 16; ++j) {
        int idx = base + j * 256 + threadIdx.x;
        if (idx < ETOT) {
            int dst = (idx < E) ? ei[E + idx] : (idx - E);
            atomicAdd(&h[dst >> 8], 1);
        }
    }
    __syncthreads();
    for (int b = threadIdx.x; b < NBUCK; b += 256)
        if (h[b]) atomicAdd(&bucketCnt[b], h[b]);
}

// single-block exclusive scan of bucket counts -> bstart, gcur
__global__ __launch_bounds__(256) void k_bscan(const int* __restrict__ bucketCnt,
                                               int* __restrict__ bstart,
                                               int* __restrict__ gcur, int ETOT) {
    __shared__ int lds[512];
    const int t = threadIdx.x;
    lds[t] = (t < NBUCK) ? bucketCnt[t] : 0;
    lds[t + 256] = (t + 256 < NBUCK) ? bucketCnt[t + 256] : 0;
    __syncthreads();
    for (int d = 1; d < 512; d <<= 1) {
        int v0 = (t >= d) ? lds[t - d] : 0;
        int v1 = (t + 256 >= d) ? lds[t + 256 - d] : 0;
        __syncthreads();
        lds[t] += v0;
        lds[t + 256] += v1;
        __syncthreads();
    }
    int e0 = (t == 0) ? 0 : lds[t - 1];
    int e1 = lds[t + 255];
    if (t < NBUCK)       { bstart[t] = e0;       gcur[t] = e0; }
    if (t + 256 < NBUCK) { bstart[t + 256] = e1; gcur[t + 256] = e1; }
    if (t == 0) bstart[NBUCK] = ETOT;
}

// block-binned placement: one global atomic per (block,bucket), then
// contiguous run writes of packed records (src | dstLocal<<17)
__global__ __launch_bounds__(256) void k_bplace(const int* __restrict__ ei, int E, int ETOT,
                                                int* __restrict__ gcur, int* __restrict__ tmp) {
    __shared__ int h[NBUCK];
    __shared__ int cur[NBUCK];
    for (int b = threadIdx.x; b < NBUCK; b += 256) h[b] = 0;
    __syncthreads();
    const int base = blockIdx.x * 4096;
    int pk[16], bk[16];
#pragma unroll
    for (int j = 0; j < 16; ++j) {
        int idx = base + j * 256 + threadIdx.x;
        bk[j] = -1;
        if (idx < ETOT) {
            int s, d;
            if (idx < E) { s = ei[idx]; d = ei[E + idx]; }
            else         { s = idx - E; d = idx - E; }
            bk[j] = d >> 8;
            pk[j] = s | ((d & 255) << 17);
            atomicAdd(&h[bk[j]], 1);
        }
    }
    __syncthreads();
    for (int b = threadIdx.x; b < NBUCK; b += 256)
        cur[b] = h[b] ? atomicAdd(&gcur[b], h[b]) : 0;
    __syncthreads();
#pragma unroll
    for (int j = 0; j < 16; ++j) {
        if (bk[j] >= 0) {
            int pos = atomicAdd(&cur[bk[j]], 1);
            tmp[pos] = pk[j];
        }
    }
}

// per-bucket exact ordering: per-node count -> scan (emits rowptr) -> place.
// all heavy reads/writes confined to this block's contiguous region.
__global__ __launch_bounds__(256) void k_bfinal(const int* __restrict__ tmp,
                                                const int* __restrict__ bstart,
                                                int* __restrict__ rowptr,
                                                int* __restrict__ ssrc, int N) {
    __shared__ int cnt[256];
    __shared__ int cur[256];
    const int t = threadIdx.x;
    const int b = blockIdx.x;
    const int s0 = bstart[b], s1 = bstart[b + 1];
    cnt[t] = 0;
    __syncthreads();
    for (int e = s0 + t; e < s1; e += 256)
        atomicAdd(&cnt[tmp[e] >> 17], 1);
    __syncthreads();
    int c0 = cnt[t];
    for (int d = 1; d < 256; d <<= 1) {
        int v = (t >= d) ? cnt[t - d] : 0;
        __syncthreads();
        cnt[t] += v;
        __syncthreads();
    }
    int excl = cnt[t] - c0;
    int node = b * 256 + t;
    if (node <= N) rowptr[node] = s0 + excl;  // node==N lands in last bucket -> ETOT
    cur[t] = excl;
    __syncthreads();
    for (int e = s0 + t; e < s1; e += 256) {
        int p = tmp[e];
        int pos = atomicAdd(&cur[p >> 17], 1);
        ssrc[s0 + pos] = p & 0x1FFFF;
    }
}

// ------------------------------ GEMM + logits -------------------------------
// xp[N][OUT] = X[N][128] @ W[128][OUT] (stored fp16); epilogue computes
// al_s[n][h] = dot(xp[n, head h], a_src[h]) (fp32 acc) and same for al_d.
template <int OUT, int H>
__global__ __launch_bounds__(256) void k_gemm(const float* __restrict__ X,
                                              const float* __restrict__ W,
                                              const float* __restrict__ a_src,
                                              const float* __restrict__ a_dst,
                                              _Float16* __restrict__ XP,
                                              float* __restrict__ al_s,
                                              float* __restrict__ al_d, int N) {
    constexpr int IN = 128;
    constexpr int ROWS = 32;
    constexpr int COLV = OUT / 4;      // float4 columns (32 or 16)
    constexpr int RGRP = 256 / COLV;   // row groups (8 or 16)
    constexpr int RT = ROWS / RGRP;    // rows per thread (4 or 2)
    constexpr int C = OUT / H;         // channels per head
    constexpr int CGH = C / 4;         // col-groups per head (8 or 16)
    __shared__ float xs[ROWS][IN];
    const int tid = threadIdx.x;
    const int row0 = blockIdx.x * ROWS;

    {
        const float4* Xv = (const float4*)(X + (size_t)row0 * IN);
        float4* xsv = (float4*)&xs[0][0];
#pragma unroll
        for (int j = 0; j < (ROWS * IN / 4) / 256; ++j)
            xsv[tid + j * 256] = Xv[tid + j * 256];
    }
    __syncthreads();

    const int cg = tid % COLV;
    const int rg = tid / COLV;
    float4 acc[RT];
#pragma unroll
    for (int r = 0; r < RT; ++r) acc[r] = make_float4(0.f, 0.f, 0.f, 0.f);

    const float4* Wv = (const float4*)W;  // [IN][COLV]
    for (int k0 = 0; k0 < IN; k0 += 4) {
        float4 w0 = Wv[(k0 + 0) * COLV + cg];
        float4 w1 = Wv[(k0 + 1) * COLV + cg];
        float4 w2 = Wv[(k0 + 2) * COLV + cg];
        float4 w3 = Wv[(k0 + 3) * COLV + cg];
#pragma unroll
        for (int r = 0; r < RT; ++r) {
            int rr = rg * RT + r;
            float4 xv = *(const float4*)&xs[rr][k0];
            acc[r].x += xv.x * w0.x + xv.y * w1.x + xv.z * w2.x + xv.w * w3.x;
            acc[r].y += xv.x * w0.y + xv.y * w1.y + xv.z * w2.y + xv.w * w3.y;
            acc[r].z += xv.x * w0.z + xv.y * w1.z + xv.z * w2.z + xv.w * w3.z;
            acc[r].w += xv.x * w0.w + xv.y * w1.w + xv.z * w2.w + xv.w * w3.w;
        }
    }
#pragma unroll
    for (int r = 0; r < RT; ++r) {
        int rr = row0 + rg * RT + r;
        half4 hv;
        hv[0] = (_Float16)acc[r].x; hv[1] = (_Float16)acc[r].y;
        hv[2] = (_Float16)acc[r].z; hv[3] = (_Float16)acc[r].w;
        *(half4*)(XP + (size_t)rr * OUT + cg * 4) = hv;
    }

    const float4 asv = ((const float4*)a_src)[cg];
    const float4 adv = ((const float4*)a_dst)[cg];
#pragma unroll
    for (int r = 0; r < RT; ++r) {
        float ps = acc[r].x * asv.x + acc[r].y * asv.y + acc[r].z * asv.z + acc[r].w * asv.w;
        float pd = acc[r].x * adv.x + acc[r].y * adv.y + acc[r].z * adv.z + acc[r].w * adv.w;
#pragma unroll
        for (int o = CGH / 2; o >= 1; o >>= 1) {
            ps += __shfl_xor(ps, o);
            pd += __shfl_xor(pd, o);
        }
        if ((cg & (CGH - 1)) == 0) {
            int rr = row0 + rg * RT + r;
            int h = cg / CGH;
            al_s[(size_t)rr * H + h] = ps;
            al_d[(size_t)rr * H + h] = pd;
        }
    }
}

// --------------------------- softmax + aggregate ----------------------------
// one wave per node, single pass (no max subtraction -- logits are O(5)).
// quarter-wave (16 lanes) per edge, 2-edge unroll -> 8 edges in flight.
template <int OUT, int H, bool ELU>
__global__ __launch_bounds__(256) void k_agg(const _Float16* __restrict__ xp,
                                             const float* __restrict__ al_s,
                                             const float* __restrict__ al_d,
                                             const int* __restrict__ rowptr,
                                             const int* __restrict__ ssrc,
                                             const float* __restrict__ bias,
                                             float* __restrict__ out, int N) {
    constexpr int C = OUT / H;
    constexpr int CPL = OUT / 16;  // fp16 channels per lane in a quarter (8 or 4)
    const int wid = threadIdx.x >> 6;
    const int lane = threadIdx.x & 63;
    const int qid = lane >> 4;   // quarter 0..3
    const int l4 = lane & 15;
    const int node = blockIdx.x * 4 + wid;
    if (node >= N) return;
    const int rs = rowptr[node];
    const int re = rowptr[node + 1];

    const int c0 = l4 * CPL;
    const int hd = c0 / C;
    const float adh = al_d[(size_t)node * H + hd];

    float ssum = 0.f;
    float acc[CPL];
#pragma unroll
    for (int j = 0; j < CPL; ++j) acc[j] = 0.f;

    int i = rs;
    for (; i + 8 <= re; i += 8) {
        int sA = ssrc[i + qid];
        int sB = ssrc[i + qid + 4];
        float eA = al_s[(size_t)sA * H + hd] + adh; eA = eA > 0.f ? eA : 0.2f * eA;
        float eB = al_s[(size_t)sB * H + hd] + adh; eB = eB > 0.f ? eB : 0.2f * eB;
        float aA = __expf(eA);
        float aB = __expf(eB);
        ssum += aA + aB;
        if constexpr (CPL == 8) {
            half8 vA = *(const half8*)(xp + (size_t)sA * OUT + c0);
            half8 vB = *(const half8*)(xp + (size_t)sB * OUT + c0);
#pragma unroll
            for (int j = 0; j < 8; ++j) acc[j] += aA * (float)vA[j] + aB * (float)vB[j];
        } else {
            half4 vA = *(const half4*)(xp + (size_t)sA * OUT + c0);
            half4 vB = *(const half4*)(xp + (size_t)sB * OUT + c0);
#pragma unroll
            for (int j = 0; j < 4; ++j) acc[j] += aA * (float)vA[j] + aB * (float)vB[j];
        }
    }
    for (; i + qid < re; i += 4) {
        int s = ssrc[i + qid];
        float e = al_s[(size_t)s * H + hd] + adh; e = e > 0.f ? e : 0.2f * e;
        float a = __expf(e);
        ssum += a;
        if constexpr (CPL == 8) {
            half8 v = *(const half8*)(xp + (size_t)s * OUT + c0);
#pragma unroll
            for (int j = 0; j < 8; ++j) acc[j] += a * (float)v[j];
        } else {
            half4 v = *(const half4*)(xp + (size_t)s * OUT + c0);
#pragma unroll
            for (int j = 0; j < 4; ++j) acc[j] += a * (float)v[j];
        }
    }

    ssum += __shfl_xor(ssum, 16);
    ssum += __shfl_xor(ssum, 32);
#pragma unroll
    for (int j = 0; j < CPL; ++j) {
        acc[j] += __shfl_xor(acc[j], 16);
        acc[j] += __shfl_xor(acc[j], 32);
    }

    if (qid == 0) {
        float inv = 1.f / (ssum + 1e-16f);
        float o[CPL];
#pragma unroll
        for (int j = 0; j < CPL; ++j) {
            o[j] = acc[j] * inv + bias[c0 + j];
            if constexpr (ELU) o[j] = o[j] > 0.f ? o[j] : (__expf(o[j]) - 1.f);
        }
        float* op = out + (size_t)node * OUT + c0;
        if constexpr (CPL == 8) {
            *(float4*)op = make_float4(o[0], o[1], o[2], o[3]);
            *(float4*)(op + 4) = make_float4(o[4], o[5], o[6], o[7]);
        } else {
            *(float4*)op = make_float4(o[0], o[1], o[2], o[3]);
        }
    }
}

// ------------------------------ launch --------------------------------------

extern "C" void kernel_launch(void* const* d_in, const int* in_sizes, int n_in,
                              void* d_out, int out_size, void* d_ws, size_t ws_size,
                              hipStream_t stream) {
    const int N = N_NODES;
    const float* x     = (const float*)d_in[0];
    const int*   ei    = (const int*)d_in[1];
    const float* W0    = (const float*)d_in[2];
    const float* as0   = (const float*)d_in[3];
    const float* ad0   = (const float*)d_in[4];
    const float* b0    = (const float*)d_in[5];
    const float* W1    = (const float*)d_in[6];
    const float* as1   = (const float*)d_in[7];
    const float* ad1   = (const float*)d_in[8];
    const float* b1    = (const float*)d_in[9];
    const float* W2    = (const float*)d_in[10];
    const float* as2   = (const float*)d_in[11];
    const float* ad2   = (const float*)d_in[12];
    const float* b2    = (const float*)d_in[13];
    float* out = (float*)d_out;

    const int E = in_sizes[1] / 2;
    const int ETOT = E + N;

    // workspace carve (256B aligned)
    char* p = (char*)d_ws;
    auto alloc = [&](size_t bytes) {
        void* r = (void*)p;
        p += (bytes + 255) & ~(size_t)255;
        return r;
    };
    _Float16* xp    = (_Float16*)alloc((size_t)N * 128 * 2);
    float* hbuf     = (float*)alloc((size_t)N * 128 * 4);
    float* als      = (float*)alloc((size_t)N * 4 * 4);
    float* ald      = (float*)alloc((size_t)N * 4 * 4);
    int*   rowptr   = (int*)alloc((size_t)(N + 1) * 4);
    int*   ssrc     = (int*)alloc((size_t)ETOT * 4);
    int*   tmp      = (int*)alloc((size_t)ETOT * 4);
    int*   bucketCnt= (int*)alloc((size_t)NBUCK * 4);
    int*   bstart   = (int*)alloc((size_t)(NBUCK + 1) * 4);
    int*   gcur     = (int*)alloc((size_t)NBUCK * 4);

    // ---- CSR build (bucket sort) ----
    const int PB = (ETOT + 4095) / 4096;
    hipMemsetAsync(bucketCnt, 0, (size_t)NBUCK * 4, stream);
    k_bcount<<<PB, 256, 0, stream>>>(ei, E, ETOT, bucketCnt);
    k_bscan<<<1, 256, 0, stream>>>(bucketCnt, bstart, gcur, ETOT);
    k_bplace<<<PB, 256, 0, stream>>>(ei, E, ETOT, gcur, tmp);
    k_bfinal<<<NBUCK, 256, 0, stream>>>(tmp, bstart, rowptr, ssrc, N);

    const int gGemm = (N + 31) / 32;
    const int gAgg  = (N + 3) / 4;

    // ---- layer 0: 128 -> 4x32, ELU ----
    k_gemm<128, 4><<<gGemm, 256, 0, stream>>>(x, W0, as0, ad0, xp, als, ald, N);
    k_agg<128, 4, true><<<gAgg, 256, 0, stream>>>(xp, als, ald, rowptr, ssrc, b0, hbuf, N);

    // ---- layer 1: 128 -> 4x32, ELU ----
    k_gemm<128, 4><<<gGemm, 256, 0, stream>>>(hbuf, W1, as1, ad1, xp, als, ald, N);
    k_agg<128, 4, true><<<gAgg, 256, 0, stream>>>(xp, als, ald, rowptr, ssrc, b1, hbuf, N);

    // ---- layer 2: 128 -> 1x64, no ELU, mean over 1 head = identity ----
    k_gemm<64, 1><<<gGemm, 256, 0, stream>>>(hbuf, W2, as2, ad2, xp, als, ald, N);
    k_agg<64, 1, false><<<gAgg, 256, 0, stream>>>(xp, als, ald, rowptr, ssrc, b2, out, N);
}

// Round 5
// 339.613 us; speedup vs baseline: 2.9986x; 1.3838x over previous
//
#include <hip/hip_runtime.h>
#include <math.h>

// ---------------------------------------------------------------------------
// GAT (3-layer PyG GATConv, eval) on MI355X.
//   CSR build: two-level bucket sort (k_bcount -> k_bscan -> k_bplace ->
//              k_bfinal), all heavy writes coalesced.
//   per layer: k_gemm = fp16 MFMA (16x16x32_f16, fp32 acc) with fused
//              attention-logit epilogue; k_agg = single-pass segment softmax
//              + aggregation + bias + ELU (quarter-wave per edge).
// R5: GEMM moved from fp32 VALU (latency-bound, 97us) to MFMA.
// ---------------------------------------------------------------------------

#define N_NODES 100000
#define NBUCK ((N_NODES + 255) / 256)   // 391 buckets of 256 nodes

typedef __attribute__((ext_vector_type(4))) _Float16 half4;
typedef __attribute__((ext_vector_type(8))) _Float16 half8;
typedef __attribute__((ext_vector_type(4))) float f32x4;

// ------------------------------ CSR build ----------------------------------

__global__ __launch_bounds__(256) void k_bcount(const int* __restrict__ ei, int E, int ETOT,
                                                int* __restrict__ bucketCnt) {
    __shared__ int h[NBUCK];
    for (int b = threadIdx.x; b < NBUCK; b += 256) h[b] = 0;
    __syncthreads();
    const int base = blockIdx.x * 4096;
#pragma unroll
    for (int j = 0; j < 16; ++j) {
        int idx = base + j * 256 + threadIdx.x;
        if (idx < ETOT) {
            int dst = (idx < E) ? ei[E + idx] : (idx - E);
            atomicAdd(&h[dst >> 8], 1);
        }
    }
    __syncthreads();
    for (int b = threadIdx.x; b < NBUCK; b += 256)
        if (h[b]) atomicAdd(&bucketCnt[b], h[b]);
}

__global__ __launch_bounds__(256) void k_bscan(const int* __restrict__ bucketCnt,
                                               int* __restrict__ bstart,
                                               int* __restrict__ gcur, int ETOT) {
    __shared__ int lds[512];
    const int t = threadIdx.x;
    lds[t] = (t < NBUCK) ? bucketCnt[t] : 0;
    lds[t + 256] = (t + 256 < NBUCK) ? bucketCnt[t + 256] : 0;
    __syncthreads();
    for (int d = 1; d < 512; d <<= 1) {
        int v0 = (t >= d) ? lds[t - d] : 0;
        int v1 = (t + 256 >= d) ? lds[t + 256 - d] : 0;
        __syncthreads();
        lds[t] += v0;
        lds[t + 256] += v1;
        __syncthreads();
    }
    int e0 = (t == 0) ? 0 : lds[t - 1];
    int e1 = lds[t + 255];
    if (t < NBUCK)       { bstart[t] = e0;       gcur[t] = e0; }
    if (t + 256 < NBUCK) { bstart[t + 256] = e1; gcur[t + 256] = e1; }
    if (t == 0) bstart[NBUCK] = ETOT;
}

__global__ __launch_bounds__(256) void k_bplace(const int* __restrict__ ei, int E, int ETOT,
                                                int* __restrict__ gcur, int* __restrict__ tmp) {
    __shared__ int h[NBUCK];
    __shared__ int cur[NBUCK];
    for (int b = threadIdx.x; b < NBUCK; b += 256) h[b] = 0;
    __syncthreads();
    const int base = blockIdx.x * 4096;
    int pk[16], bk[16];
#pragma unroll
    for (int j = 0; j < 16; ++j) {
        int idx = base + j * 256 + threadIdx.x;
        bk[j] = -1;
        if (idx < ETOT) {
            int s, d;
            if (idx < E) { s = ei[idx]; d = ei[E + idx]; }
            else         { s = idx - E; d = idx - E; }
            bk[j] = d >> 8;
            pk[j] = s | ((d & 255) << 17);
            atomicAdd(&h[bk[j]], 1);
        }
    }
    __syncthreads();
    for (int b = threadIdx.x; b < NBUCK; b += 256)
        cur[b] = h[b] ? atomicAdd(&gcur[b], h[b]) : 0;
    __syncthreads();
#pragma unroll
    for (int j = 0; j < 16; ++j) {
        if (bk[j] >= 0) {
            int pos = atomicAdd(&cur[bk[j]], 1);
            tmp[pos] = pk[j];
        }
    }
}

__global__ __launch_bounds__(256) void k_bfinal(const int* __restrict__ tmp,
                                                const int* __restrict__ bstart,
                                                int* __restrict__ rowptr,
                                                int* __restrict__ ssrc, int N) {
    __shared__ int cnt[256];
    __shared__ int cur[256];
    const int t = threadIdx.x;
    const int b = blockIdx.x;
    const int s0 = bstart[b], s1 = bstart[b + 1];
    cnt[t] = 0;
    __syncthreads();
    for (int e = s0 + t; e < s1; e += 256)
        atomicAdd(&cnt[tmp[e] >> 17], 1);
    __syncthreads();
    int c0 = cnt[t];
    for (int d = 1; d < 256; d <<= 1) {
        int v = (t >= d) ? cnt[t - d] : 0;
        __syncthreads();
        cnt[t] += v;
        __syncthreads();
    }
    int excl = cnt[t] - c0;
    int node = b * 256 + t;
    if (node <= N) rowptr[node] = s0 + excl;
    cur[t] = excl;
    __syncthreads();
    for (int e = s0 + t; e < s1; e += 256) {
        int p = tmp[e];
        int pos = atomicAdd(&cur[p >> 17], 1);
        ssrc[s0 + pos] = p & 0x1FFFF;
    }
}

// --------------------------- W transpose to fp16 ----------------------------
__global__ void k_wt(const float* __restrict__ W, _Float16* __restrict__ Wt, int OUTn) {
    int idx = blockIdx.x * 256 + threadIdx.x;
    if (idx >= 128 * OUTn) return;
    int k = idx / OUTn, n = idx % OUTn;
    Wt[n * 128 + k] = (_Float16)W[idx];
}

// ------------------------------ MFMA GEMM + logits --------------------------
// xp[N][OUT] = X[N][128] @ W[128][OUT]; A,B fp16 in LDS (padded rows),
// fp32 MFMA accumulate. Fused epilogue computes al_s/al_d.
// C/D layout (m89): col = lane&15, row = (lane>>4)*4 + reg.
template <int OUT, int H>
__global__ __launch_bounds__(256) void k_gemm(const float* __restrict__ X,
                                              const _Float16* __restrict__ Wt,
                                              const float* __restrict__ a_src,
                                              const float* __restrict__ a_dst,
                                              _Float16* __restrict__ XP,
                                              float* __restrict__ al_s,
                                              float* __restrict__ al_d, int N) {
    constexpr int NT = OUT / 16;   // n-tiles per wave (8 or 4)
    constexpr int C = OUT / H;     // channels per head
    constexpr int LDH = 136;       // padded halfs per LDS row (272B -> 4-bank skew)
    __shared__ _Float16 As[64 * LDH];
    __shared__ _Float16 Ws[OUT * LDH];
    const int tid = threadIdx.x;
    const int row0 = blockIdx.x * 64;

    // stage Wt[OUT][128] -> Ws (coalesced half8)
    for (int c = tid; c < OUT * 16; c += 256) {
        int r = c >> 4, kc = c & 15;
        *(half8*)&Ws[r * LDH + kc * 8] = *(const half8*)(Wt + r * 128 + kc * 8);
    }
    // stage X rows -> As (fp32 -> fp16)
    for (int c = tid; c < 64 * 16; c += 256) {
        int r = c >> 4, kc = c & 15;
        int grow = row0 + r;
        half8 hv;
        if (grow < N) {
            const float4* xr = (const float4*)(X + (size_t)grow * 128 + kc * 8);
            float4 x0 = xr[0], x1 = xr[1];
            hv[0] = (_Float16)x0.x; hv[1] = (_Float16)x0.y;
            hv[2] = (_Float16)x0.z; hv[3] = (_Float16)x0.w;
            hv[4] = (_Float16)x1.x; hv[5] = (_Float16)x1.y;
            hv[6] = (_Float16)x1.z; hv[7] = (_Float16)x1.w;
        } else {
#pragma unroll
            for (int j = 0; j < 8; ++j) hv[j] = (_Float16)0.f;
        }
        *(half8*)&As[r * LDH + kc * 8] = hv;
    }
    __syncthreads();

    const int w = tid >> 6;
    const int l = tid & 63;
    const int lm = l & 15;
    const int lk = l >> 4;

    f32x4 acc[NT];
#pragma unroll
    for (int nt = 0; nt < NT; ++nt) acc[nt] = {0.f, 0.f, 0.f, 0.f};

#pragma unroll
    for (int ks = 0; ks < 4; ++ks) {
        half8 av = *(const half8*)&As[(w * 16 + lm) * LDH + ks * 32 + lk * 8];
#pragma unroll
        for (int nt = 0; nt < NT; ++nt) {
            half8 bv = *(const half8*)&Ws[(nt * 16 + lm) * LDH + ks * 32 + lk * 8];
            acc[nt] = __builtin_amdgcn_mfma_f32_16x16x32_f16(av, bv, acc[nt], 0, 0, 0);
        }
    }

    // per-lane attention-vector gathers (col = nt*16 + lm)
    float avs[NT], avd[NT];
#pragma unroll
    for (int nt = 0; nt < NT; ++nt) {
        avs[nt] = a_src[nt * 16 + lm];
        avd[nt] = a_dst[nt * 16 + lm];
    }

#pragma unroll
    for (int r = 0; r < 4; ++r) {
        int grow = row0 + w * 16 + lk * 4 + r;
        bool ok = grow < N;
#pragma unroll
        for (int nt = 0; nt < NT; ++nt)
            if (ok) XP[(size_t)grow * OUT + nt * 16 + lm] = (_Float16)acc[nt][r];

        float ps[H], pd[H];
#pragma unroll
        for (int h = 0; h < H; ++h) { ps[h] = 0.f; pd[h] = 0.f; }
#pragma unroll
        for (int nt = 0; nt < NT; ++nt) {
            int h = (nt * 16) / C;  // constant after unroll
            ps[h] += acc[nt][r] * avs[nt];
            pd[h] += acc[nt][r] * avd[nt];
        }
#pragma unroll
        for (int h = 0; h < H; ++h) {
#pragma unroll
            for (int o = 8; o >= 1; o >>= 1) {
                ps[h] += __shfl_xor(ps[h], o);
                pd[h] += __shfl_xor(pd[h], o);
            }
        }
        if (ok && lm == 0) {
#pragma unroll
            for (int h = 0; h < H; ++h) {
                al_s[(size_t)grow * H + h] = ps[h];
                al_d[(size_t)grow * H + h] = pd[h];
            }
        }
    }
}

// --------------------------- softmax + aggregate ----------------------------
template <int OUT, int H, bool ELU>
__global__ __launch_bounds__(256) void k_agg(const _Float16* __restrict__ xp,
                                             const float* __restrict__ al_s,
                                             const float* __restrict__ al_d,
                                             const int* __restrict__ rowptr,
                                             const int* __restrict__ ssrc,
                                             const float* __restrict__ bias,
                                             float* __restrict__ out, int N) {
    constexpr int C = OUT / H;
    constexpr int CPL = OUT / 16;
    const int wid = threadIdx.x >> 6;
    const int lane = threadIdx.x & 63;
    const int qid = lane >> 4;
    const int l4 = lane & 15;
    const int node = blockIdx.x * 4 + wid;
    if (node >= N) return;
    const int rs = rowptr[node];
    const int re = rowptr[node + 1];

    const int c0 = l4 * CPL;
    const int hd = c0 / C;
    const float adh = al_d[(size_t)node * H + hd];

    float ssum = 0.f;
    float acc[CPL];
#pragma unroll
    for (int j = 0; j < CPL; ++j) acc[j] = 0.f;

    int i = rs;
    for (; i + 8 <= re; i += 8) {
        int sA = ssrc[i + qid];
        int sB = ssrc[i + qid + 4];
        float eA = al_s[(size_t)sA * H + hd] + adh; eA = eA > 0.f ? eA : 0.2f * eA;
        float eB = al_s[(size_t)sB * H + hd] + adh; eB = eB > 0.f ? eB : 0.2f * eB;
        float aA = __expf(eA);
        float aB = __expf(eB);
        ssum += aA + aB;
        if constexpr (CPL == 8) {
            half8 vA = *(const half8*)(xp + (size_t)sA * OUT + c0);
            half8 vB = *(const half8*)(xp + (size_t)sB * OUT + c0);
#pragma unroll
            for (int j = 0; j < 8; ++j) acc[j] += aA * (float)vA[j] + aB * (float)vB[j];
        } else {
            half4 vA = *(const half4*)(xp + (size_t)sA * OUT + c0);
            half4 vB = *(const half4*)(xp + (size_t)sB * OUT + c0);
#pragma unroll
            for (int j = 0; j < 4; ++j) acc[j] += aA * (float)vA[j] + aB * (float)vB[j];
        }
    }
    for (; i + qid < re; i += 4) {
        int s = ssrc[i + qid];
        float e = al_s[(size_t)s * H + hd] + adh; e = e > 0.f ? e : 0.2f * e;
        float a = __expf(e);
        ssum += a;
        if constexpr (CPL == 8) {
            half8 v = *(const half8*)(xp + (size_t)s * OUT + c0);
#pragma unroll
            for (int j = 0; j < 8; ++j) acc[j] += a * (float)v[j];
        } else {
            half4 v = *(const half4*)(xp + (size_t)s * OUT + c0);
#pragma unroll
            for (int j = 0; j < 4; ++j) acc[j] += a * (float)v[j];
        }
    }

    ssum += __shfl_xor(ssum, 16);
    ssum += __shfl_xor(ssum, 32);
#pragma unroll
    for (int j = 0; j < CPL; ++j) {
        acc[j] += __shfl_xor(acc[j], 16);
        acc[j] += __shfl_xor(acc[j], 32);
    }

    if (qid == 0) {
        float inv = 1.f / (ssum + 1e-16f);
        float o[CPL];
#pragma unroll
        for (int j = 0; j < CPL; ++j) {
            o[j] = acc[j] * inv + bias[c0 + j];
            if constexpr (ELU) o[j] = o[j] > 0.f ? o[j] : (__expf(o[j]) - 1.f);
        }
        float* op = out + (size_t)node * OUT + c0;
        if constexpr (CPL == 8) {
            *(float4*)op = make_float4(o[0], o[1], o[2], o[3]);
            *(float4*)(op + 4) = make_float4(o[4], o[5], o[6], o[7]);
        } else {
            *(float4*)op = make_float4(o[0], o[1], o[2], o[3]);
        }
    }
}

// ------------------------------ launch --------------------------------------

extern "C" void kernel_launch(void* const* d_in, const int* in_sizes, int n_in,
                              void* d_out, int out_size, void* d_ws, size_t ws_size,
                              hipStream_t stream) {
    const int N = N_NODES;
    const float* x     = (const float*)d_in[0];
    const int*   ei    = (const int*)d_in[1];
    const float* W0    = (const float*)d_in[2];
    const float* as0   = (const float*)d_in[3];
    const float* ad0   = (const float*)d_in[4];
    const float* b0    = (const float*)d_in[5];
    const float* W1    = (const float*)d_in[6];
    const float* as1   = (const float*)d_in[7];
    const float* ad1   = (const float*)d_in[8];
    const float* b1    = (const float*)d_in[9];
    const float* W2    = (const float*)d_in[10];
    const float* as2   = (const float*)d_in[11];
    const float* ad2   = (const float*)d_in[12];
    const float* b2    = (const float*)d_in[13];
    float* out = (float*)d_out;

    const int E = in_sizes[1] / 2;
    const int ETOT = E + N;

    char* p = (char*)d_ws;
    auto alloc = [&](size_t bytes) {
        void* r = (void*)p;
        p += (bytes + 255) & ~(size_t)255;
        return r;
    };
    _Float16* xp    = (_Float16*)alloc((size_t)N * 128 * 2);
    float* hbuf     = (float*)alloc((size_t)N * 128 * 4);
    float* als      = (float*)alloc((size_t)N * 4 * 4);
    float* ald      = (float*)alloc((size_t)N * 4 * 4);
    int*   rowptr   = (int*)alloc((size_t)(N + 1) * 4);
    int*   ssrc     = (int*)alloc((size_t)ETOT * 4);
    int*   tmp      = (int*)alloc((size_t)ETOT * 4);
    int*   bucketCnt= (int*)alloc((size_t)NBUCK * 4);
    int*   bstart   = (int*)alloc((size_t)(NBUCK + 1) * 4);
    int*   gcur     = (int*)alloc((size_t)NBUCK * 4);
    _Float16* wt0   = (_Float16*)alloc((size_t)128 * 128 * 2);
    _Float16* wt1   = (_Float16*)alloc((size_t)128 * 128 * 2);
    _Float16* wt2   = (_Float16*)alloc((size_t)128 * 64 * 2);

    // ---- W transposes (independent of CSR) ----
    k_wt<<<64, 256, 0, stream>>>(W0, wt0, 128);
    k_wt<<<64, 256, 0, stream>>>(W1, wt1, 128);
    k_wt<<<32, 256, 0, stream>>>(W2, wt2, 64);

    // ---- CSR build (bucket sort) ----
    const int PB = (ETOT + 4095) / 4096;
    hipMemsetAsync(bucketCnt, 0, (size_t)NBUCK * 4, stream);
    k_bcount<<<PB, 256, 0, stream>>>(ei, E, ETOT, bucketCnt);
    k_bscan<<<1, 256, 0, stream>>>(bucketCnt, bstart, gcur, ETOT);
    k_bplace<<<PB, 256, 0, stream>>>(ei, E, ETOT, gcur, tmp);
    k_bfinal<<<NBUCK, 256, 0, stream>>>(tmp, bstart, rowptr, ssrc, N);

    const int gGemm = (N + 63) / 64;
    const int gAgg  = (N + 3) / 4;

    // ---- layer 0: 128 -> 4x32, ELU ----
    k_gemm<128, 4><<<gGemm, 256, 0, stream>>>(x, wt0, as0, ad0, xp, als, ald, N);
    k_agg<128, 4, true><<<gAgg, 256, 0, stream>>>(xp, als, ald, rowptr, ssrc, b0, hbuf, N);

    // ---- layer 1: 128 -> 4x32, ELU ----
    k_gemm<128, 4><<<gGemm, 256, 0, stream>>>(hbuf, wt1, as1, ad1, xp, als, ald, N);
    k_agg<128, 4, true><<<gAgg, 256, 0, stream>>>(xp, als, ald, rowptr, ssrc, b1, hbuf, N);

    // ---- layer 2: 128 -> 1x64, no ELU ----
    k_gemm<64, 1><<<gGemm, 256, 0, stream>>>(hbuf, wt2, as2, ad2, xp, als, ald, N);
    k_agg<64, 1, false><<<gAgg, 256, 0, stream>>>(xp, als, ald, rowptr, ssrc, b2, out, N);
}

// Round 6
// 321.950 us; speedup vs baseline: 3.1631x; 1.0549x over previous
//
#include <hip/hip_runtime.h>
#include <math.h>

// ---------------------------------------------------------------------------
// GAT (3-layer PyG GATConv, eval) on MI355X.
//   CSR build: two-level bucket sort (k_bcount -> k_bscan -> k_bplace ->
//              k_bfinal), all heavy writes coalesced.
//   per layer: k_gemm = fp16 MFMA (16x16x32_f16, fp32 acc) with fused
//              attention-logit epilogue; k_agg = single-pass segment softmax
//              + aggregation + bias + ELU (quarter-wave per edge).
// R6: 16-edge-deep gather pipeline in k_agg; fp16 hidden state (zero extra
//     rounding -- GEMM staging converted to fp16 anyway); fused k_wt3.
// ---------------------------------------------------------------------------

#define N_NODES 100000
#define NBUCK ((N_NODES + 255) / 256)   // 391 buckets of 256 nodes

typedef __attribute__((ext_vector_type(4))) _Float16 half4;
typedef __attribute__((ext_vector_type(8))) _Float16 half8;
typedef __attribute__((ext_vector_type(4))) float f32x4;

// ------------------------------ CSR build ----------------------------------

__global__ __launch_bounds__(256) void k_bcount(const int* __restrict__ ei, int E, int ETOT,
                                                int* __restrict__ bucketCnt) {
    __shared__ int h[NBUCK];
    for (int b = threadIdx.x; b < NBUCK; b += 256) h[b] = 0;
    __syncthreads();
    const int base = blockIdx.x * 4096;
#pragma unroll
    for (int j = 0; j < 16; ++j) {
        int idx = base + j * 256 + threadIdx.x;
        if (idx < ETOT) {
            int dst = (idx < E) ? ei[E + idx] : (idx - E);
            atomicAdd(&h[dst >> 8], 1);
        }
    }
    __syncthreads();
    for (int b = threadIdx.x; b < NBUCK; b += 256)
        if (h[b]) atomicAdd(&bucketCnt[b], h[b]);
}

__global__ __launch_bounds__(256) void k_bscan(const int* __restrict__ bucketCnt,
                                               int* __restrict__ bstart,
                                               int* __restrict__ gcur, int ETOT) {
    __shared__ int lds[512];
    const int t = threadIdx.x;
    lds[t] = (t < NBUCK) ? bucketCnt[t] : 0;
    lds[t + 256] = (t + 256 < NBUCK) ? bucketCnt[t + 256] : 0;
    __syncthreads();
    for (int d = 1; d < 512; d <<= 1) {
        int v0 = (t >= d) ? lds[t - d] : 0;
        int v1 = (t + 256 >= d) ? lds[t + 256 - d] : 0;
        __syncthreads();
        lds[t] += v0;
        lds[t + 256] += v1;
        __syncthreads();
    }
    int e0 = (t == 0) ? 0 : lds[t - 1];
    int e1 = lds[t + 255];
    if (t < NBUCK)       { bstart[t] = e0;       gcur[t] = e0; }
    if (t + 256 < NBUCK) { bstart[t + 256] = e1; gcur[t + 256] = e1; }
    if (t == 0) bstart[NBUCK] = ETOT;
}

__global__ __launch_bounds__(256) void k_bplace(const int* __restrict__ ei, int E, int ETOT,
                                                int* __restrict__ gcur, int* __restrict__ tmp) {
    __shared__ int h[NBUCK];
    __shared__ int cur[NBUCK];
    for (int b = threadIdx.x; b < NBUCK; b += 256) h[b] = 0;
    __syncthreads();
    const int base = blockIdx.x * 4096;
    int pk[16], bk[16];
#pragma unroll
    for (int j = 0; j < 16; ++j) {
        int idx = base + j * 256 + threadIdx.x;
        bk[j] = -1;
        if (idx < ETOT) {
            int s, d;
            if (idx < E) { s = ei[idx]; d = ei[E + idx]; }
            else         { s = idx - E; d = idx - E; }
            bk[j] = d >> 8;
            pk[j] = s | ((d & 255) << 17);
            atomicAdd(&h[bk[j]], 1);
        }
    }
    __syncthreads();
    for (int b = threadIdx.x; b < NBUCK; b += 256)
        cur[b] = h[b] ? atomicAdd(&gcur[b], h[b]) : 0;
    __syncthreads();
#pragma unroll
    for (int j = 0; j < 16; ++j) {
        if (bk[j] >= 0) {
            int pos = atomicAdd(&cur[bk[j]], 1);
            tmp[pos] = pk[j];
        }
    }
}

__global__ __launch_bounds__(256) void k_bfinal(const int* __restrict__ tmp,
                                                const int* __restrict__ bstart,
                                                int* __restrict__ rowptr,
                                                int* __restrict__ ssrc, int N) {
    __shared__ int cnt[256];
    __shared__ int cur[256];
    const int t = threadIdx.x;
    const int b = blockIdx.x;
    const int s0 = bstart[b], s1 = bstart[b + 1];
    cnt[t] = 0;
    __syncthreads();
    for (int e = s0 + t; e < s1; e += 256)
        atomicAdd(&cnt[tmp[e] >> 17], 1);
    __syncthreads();
    int c0 = cnt[t];
    for (int d = 1; d < 256; d <<= 1) {
        int v = (t >= d) ? cnt[t - d] : 0;
        __syncthreads();
        cnt[t] += v;
        __syncthreads();
    }
    int excl = cnt[t] - c0;
    int node = b * 256 + t;
    if (node <= N) rowptr[node] = s0 + excl;
    cur[t] = excl;
    __syncthreads();
    for (int e = s0 + t; e < s1; e += 256) {
        int p = tmp[e];
        int pos = atomicAdd(&cur[p >> 17], 1);
        ssrc[s0 + pos] = p & 0x1FFFF;
    }
}

// --------------------------- W transposes to fp16 ---------------------------
__global__ void k_wt3(const float* __restrict__ W0, const float* __restrict__ W1,
                      const float* __restrict__ W2, _Float16* __restrict__ wt0,
                      _Float16* __restrict__ wt1, _Float16* __restrict__ wt2) {
    int idx = blockIdx.x * 256 + threadIdx.x;
    if (idx < 16384) {
        int k = idx >> 7, n = idx & 127;
        wt0[n * 128 + k] = (_Float16)W0[idx];
    } else if (idx < 32768) {
        int i = idx - 16384;
        int k = i >> 7, n = i & 127;
        wt1[n * 128 + k] = (_Float16)W1[i];
    } else if (idx < 40960) {
        int i = idx - 32768;
        int k = i >> 6, n = i & 63;
        wt2[n * 128 + k] = (_Float16)W2[i];
    }
}

// ------------------------------ MFMA GEMM + logits --------------------------
// xp[N][OUT] = X[N][128] @ W[128][OUT]; A,B fp16 in LDS (padded rows),
// fp32 MFMA accumulate. Fused epilogue computes al_s/al_d.
// C/D layout (m89): col = lane&15, row = (lane>>4)*4 + reg.
template <int OUT, int H, bool INF16>
__global__ __launch_bounds__(256) void k_gemm(const void* __restrict__ Xv_,
                                              const _Float16* __restrict__ Wt,
                                              const float* __restrict__ a_src,
                                              const float* __restrict__ a_dst,
                                              _Float16* __restrict__ XP,
                                              float* __restrict__ al_s,
                                              float* __restrict__ al_d, int N) {
    constexpr int NT = OUT / 16;   // n-tiles per wave (8 or 4)
    constexpr int C = OUT / H;     // channels per head
    constexpr int LDH = 136;       // padded halfs per LDS row (272B -> 4-bank skew)
    __shared__ _Float16 As[64 * LDH];
    __shared__ _Float16 Ws[OUT * LDH];
    const int tid = threadIdx.x;
    const int row0 = blockIdx.x * 64;

    // stage Wt[OUT][128] -> Ws (coalesced half8)
    for (int c = tid; c < OUT * 16; c += 256) {
        int r = c >> 4, kc = c & 15;
        *(half8*)&Ws[r * LDH + kc * 8] = *(const half8*)(Wt + r * 128 + kc * 8);
    }
    // stage X rows -> As
    for (int c = tid; c < 64 * 16; c += 256) {
        int r = c >> 4, kc = c & 15;
        int grow = row0 + r;
        half8 hv;
        if (grow < N) {
            if constexpr (INF16) {
                hv = *(const half8*)((const _Float16*)Xv_ + (size_t)grow * 128 + kc * 8);
            } else {
                const float4* xr = (const float4*)((const float*)Xv_ + (size_t)grow * 128 + kc * 8);
                float4 x0 = xr[0], x1 = xr[1];
                hv[0] = (_Float16)x0.x; hv[1] = (_Float16)x0.y;
                hv[2] = (_Float16)x0.z; hv[3] = (_Float16)x0.w;
                hv[4] = (_Float16)x1.x; hv[5] = (_Float16)x1.y;
                hv[6] = (_Float16)x1.z; hv[7] = (_Float16)x1.w;
            }
        } else {
#pragma unroll
            for (int j = 0; j < 8; ++j) hv[j] = (_Float16)0.f;
        }
        *(half8*)&As[r * LDH + kc * 8] = hv;
    }
    __syncthreads();

    const int w = tid >> 6;
    const int l = tid & 63;
    const int lm = l & 15;
    const int lk = l >> 4;

    f32x4 acc[NT];
#pragma unroll
    for (int nt = 0; nt < NT; ++nt) acc[nt] = {0.f, 0.f, 0.f, 0.f};

#pragma unroll
    for (int ks = 0; ks < 4; ++ks) {
        half8 av = *(const half8*)&As[(w * 16 + lm) * LDH + ks * 32 + lk * 8];
#pragma unroll
        for (int nt = 0; nt < NT; ++nt) {
            half8 bv = *(const half8*)&Ws[(nt * 16 + lm) * LDH + ks * 32 + lk * 8];
            acc[nt] = __builtin_amdgcn_mfma_f32_16x16x32_f16(av, bv, acc[nt], 0, 0, 0);
        }
    }

    float avs[NT], avd[NT];
#pragma unroll
    for (int nt = 0; nt < NT; ++nt) {
        avs[nt] = a_src[nt * 16 + lm];
        avd[nt] = a_dst[nt * 16 + lm];
    }

#pragma unroll
    for (int r = 0; r < 4; ++r) {
        int grow = row0 + w * 16 + lk * 4 + r;
        bool ok = grow < N;
#pragma unroll
        for (int nt = 0; nt < NT; ++nt)
            if (ok) XP[(size_t)grow * OUT + nt * 16 + lm] = (_Float16)acc[nt][r];

        float ps[H], pd[H];
#pragma unroll
        for (int h = 0; h < H; ++h) { ps[h] = 0.f; pd[h] = 0.f; }
#pragma unroll
        for (int nt = 0; nt < NT; ++nt) {
            int h = (nt * 16) / C;  // constant after unroll
            ps[h] += acc[nt][r] * avs[nt];
            pd[h] += acc[nt][r] * avd[nt];
        }
#pragma unroll
        for (int h = 0; h < H; ++h) {
#pragma unroll
            for (int o = 8; o >= 1; o >>= 1) {
                ps[h] += __shfl_xor(ps[h], o);
                pd[h] += __shfl_xor(pd[h], o);
            }
        }
        if (ok && lm == 0) {
#pragma unroll
            for (int h = 0; h < H; ++h) {
                al_s[(size_t)grow * H + h] = ps[h];
                al_d[(size_t)grow * H + h] = pd[h];
            }
        }
    }
}

// --------------------------- softmax + aggregate ----------------------------
// one wave per node, single pass. quarter-wave (16 lanes) per edge,
// 16-edge main trips -> 16 gathers in flight per wave.
template <int OUT, int H, bool ELU, bool OUTF16>
__global__ __launch_bounds__(256) void k_agg(const _Float16* __restrict__ xp,
                                             const float* __restrict__ al_s,
                                             const float* __restrict__ al_d,
                                             const int* __restrict__ rowptr,
                                             const int* __restrict__ ssrc,
                                             const float* __restrict__ bias,
                                             void* __restrict__ out_, int N) {
    constexpr int C = OUT / H;
    constexpr int CPL = OUT / 16;  // fp16 channels per lane in a quarter (8 or 4)
    const int wid = threadIdx.x >> 6;
    const int lane = threadIdx.x & 63;
    const int qid = lane >> 4;
    const int l4 = lane & 15;
    const int node = blockIdx.x * 4 + wid;
    if (node >= N) return;
    const int rs = rowptr[node];
    const int re = rowptr[node + 1];

    const int c0 = l4 * CPL;
    const int hd = c0 / C;
    const float adh = al_d[(size_t)node * H + hd];

    float ssum = 0.f;
    float acc[CPL];
#pragma unroll
    for (int j = 0; j < CPL; ++j) acc[j] = 0.f;

    auto edge = [&](int idx) {
        int s = ssrc[idx];
        float e = al_s[(size_t)s * H + hd] + adh;
        e = e > 0.f ? e : 0.2f * e;
        float a = __expf(e);
        ssum += a;
        if constexpr (CPL == 8) {
            half8 v = *(const half8*)(xp + (size_t)s * OUT + c0);
#pragma unroll
            for (int j = 0; j < 8; ++j) acc[j] += a * (float)v[j];
        } else {
            half4 v = *(const half4*)(xp + (size_t)s * OUT + c0);
#pragma unroll
            for (int j = 0; j < 4; ++j) acc[j] += a * (float)v[j];
        }
    };

    int i = rs;
    for (; i + 16 <= re; i += 16) {
        edge(i + qid); edge(i + qid + 4); edge(i + qid + 8); edge(i + qid + 12);
    }
    for (; i + 8 <= re; i += 8) {
        edge(i + qid); edge(i + qid + 4);
    }
    for (; i + qid < re; i += 4) {
        edge(i + qid);
    }

    ssum += __shfl_xor(ssum, 16);
    ssum += __shfl_xor(ssum, 32);
#pragma unroll
    for (int j = 0; j < CPL; ++j) {
        acc[j] += __shfl_xor(acc[j], 16);
        acc[j] += __shfl_xor(acc[j], 32);
    }

    if (qid == 0) {
        float inv = 1.f / (ssum + 1e-16f);
        float o[CPL];
#pragma unroll
        for (int j = 0; j < CPL; ++j) {
            o[j] = acc[j] * inv + bias[c0 + j];
            if constexpr (ELU) o[j] = o[j] > 0.f ? o[j] : (__expf(o[j]) - 1.f);
        }
        if constexpr (OUTF16) {
            _Float16* op = (_Float16*)out_ + (size_t)node * OUT + c0;
            if constexpr (CPL == 8) {
                half8 hv;
#pragma unroll
                for (int j = 0; j < 8; ++j) hv[j] = (_Float16)o[j];
                *(half8*)op = hv;
            } else {
                half4 hv;
#pragma unroll
                for (int j = 0; j < 4; ++j) hv[j] = (_Float16)o[j];
                *(half4*)op = hv;
            }
        } else {
            float* op = (float*)out_ + (size_t)node * OUT + c0;
            if constexpr (CPL == 8) {
                *(float4*)op = make_float4(o[0], o[1], o[2], o[3]);
                *(float4*)(op + 4) = make_float4(o[4], o[5], o[6], o[7]);
            } else {
                *(float4*)op = make_float4(o[0], o[1], o[2], o[3]);
            }
        }
    }
}

// ------------------------------ launch --------------------------------------

extern "C" void kernel_launch(void* const* d_in, const int* in_sizes, int n_in,
                              void* d_out, int out_size, void* d_ws, size_t ws_size,
                              hipStream_t stream) {
    const int N = N_NODES;
    const float* x     = (const float*)d_in[0];
    const int*   ei    = (const int*)d_in[1];
    const float* W0    = (const float*)d_in[2];
    const float* as0   = (const float*)d_in[3];
    const float* ad0   = (const float*)d_in[4];
    const float* b0    = (const float*)d_in[5];
    const float* W1    = (const float*)d_in[6];
    const float* as1   = (const float*)d_in[7];
    const float* ad1   = (const float*)d_in[8];
    const float* b1    = (const float*)d_in[9];
    const float* W2    = (const float*)d_in[10];
    const float* as2   = (const float*)d_in[11];
    const float* ad2   = (const float*)d_in[12];
    const float* b2    = (const float*)d_in[13];
    float* out = (float*)d_out;

    const int E = in_sizes[1] / 2;
    const int ETOT = E + N;

    char* p = (char*)d_ws;
    auto alloc = [&](size_t bytes) {
        void* r = (void*)p;
        p += (bytes + 255) & ~(size_t)255;
        return r;
    };
    _Float16* xp    = (_Float16*)alloc((size_t)N * 128 * 2);
    _Float16* hbuf  = (_Float16*)alloc((size_t)N * 128 * 2);
    float* als      = (float*)alloc((size_t)N * 4 * 4);
    float* ald      = (float*)alloc((size_t)N * 4 * 4);
    int*   rowptr   = (int*)alloc((size_t)(N + 1) * 4);
    int*   ssrc     = (int*)alloc((size_t)ETOT * 4);
    int*   tmp      = (int*)alloc((size_t)ETOT * 4);
    int*   bucketCnt= (int*)alloc((size_t)NBUCK * 4);
    int*   bstart   = (int*)alloc((size_t)(NBUCK + 1) * 4);
    int*   gcur     = (int*)alloc((size_t)NBUCK * 4);
    _Float16* wt0   = (_Float16*)alloc((size_t)128 * 128 * 2);
    _Float16* wt1   = (_Float16*)alloc((size_t)128 * 128 * 2);
    _Float16* wt2   = (_Float16*)alloc((size_t)128 * 64 * 2);

    // ---- W transposes (one fused launch) ----
    k_wt3<<<160, 256, 0, stream>>>(W0, W1, W2, wt0, wt1, wt2);

    // ---- CSR build (bucket sort) ----
    const int PB = (ETOT + 4095) / 4096;
    hipMemsetAsync(bucketCnt, 0, (size_t)NBUCK * 4, stream);
    k_bcount<<<PB, 256, 0, stream>>>(ei, E, ETOT, bucketCnt);
    k_bscan<<<1, 256, 0, stream>>>(bucketCnt, bstart, gcur, ETOT);
    k_bplace<<<PB, 256, 0, stream>>>(ei, E, ETOT, gcur, tmp);
    k_bfinal<<<NBUCK, 256, 0, stream>>>(tmp, bstart, rowptr, ssrc, N);

    const int gGemm = (N + 63) / 64;
    const int gAgg  = (N + 3) / 4;

    // ---- layer 0: 128 -> 4x32, ELU ----
    k_gemm<128, 4, false><<<gGemm, 256, 0, stream>>>(x, wt0, as0, ad0, xp, als, ald, N);
    k_agg<128, 4, true, true><<<gAgg, 256, 0, stream>>>(xp, als, ald, rowptr, ssrc, b0, hbuf, N);

    // ---- layer 1: 128 -> 4x32, ELU ----
    k_gemm<128, 4, true><<<gGemm, 256, 0, stream>>>(hbuf, wt1, as1, ad1, xp, als, ald, N);
    k_agg<128, 4, true, true><<<gAgg, 256, 0, stream>>>(xp, als, ald, rowptr, ssrc, b1, hbuf, N);

    // ---- layer 2: 128 -> 1x64, no ELU ----
    k_gemm<64, 1, true><<<gGemm, 256, 0, stream>>>(hbuf, wt2, as2, ad2, xp, als, ald, N);
    k_agg<64, 1, false, false><<<gAgg, 256, 0, stream>>>(xp, als, ald, rowptr, ssrc, b2, out, N);
}